// Round 14
// baseline (142.424 us; speedup 1.0000x reference)
//
#include <hip/hip_runtime.h>
#include <stdint.h>

// ---------------------------------------------------------------------------
// TransformerXL encoder layer.  Inputs fp32, OUTPUT fp32.  b=4 l=1024 d=512
// h=8 dh=64.
// Round 14: attn arithmetic-intensity restructure.  8 waves x 32 q-rows
// (2 row-groups share every B-frag read: content 8 reads/16 MFMA, band 6
// shared frags/20 MFMA, PV vb shared), 256-row q-blocks, KV-split x2 for
// grid 256 (1 block/CU, 8 waves/CU), shared 320-row rk band, partial
// (O,m,l) + merge kernel (round-11 style).  GPU-wide LDS b128 reads -43%.
// rel shift closed form: shifted[t,j] = R[t, 1024 + j - t],  R = (q+rb)@rk^T.
// ---------------------------------------------------------------------------

typedef unsigned short u16;
typedef __attribute__((ext_vector_type(8))) __bf16 bf16x8;
typedef __attribute__((ext_vector_type(8))) unsigned short u16x8;
typedef __attribute__((ext_vector_type(4))) float f32x4;
typedef __attribute__((ext_vector_type(2))) float f32x2;
typedef __attribute__((ext_vector_type(4))) unsigned short u16x4;

#define BK 64

static __device__ __forceinline__ u16 f2bf(float f) {
  union { float f; unsigned int i; } v; v.f = f;
  unsigned int r = v.i + 0x7FFFu + ((v.i >> 16) & 1u);
  return (u16)(r >> 16);
}

// global->LDS direct copy, 16B per lane (lds dest must be linear in lane id).
static __device__ __forceinline__ void gld16(const void* g, void* l) {
  __builtin_amdgcn_global_load_lds(
      (__attribute__((address_space(1))) void*)(uintptr_t)g,
      (__attribute__((address_space(3))) void*)(uintptr_t)l,
      16, 0, 0);
}

// swizzled u16 index into a [rows][64]-u16 LDS tile (16B chunk ^= row&7).
static __device__ __forceinline__ int swzIdx(int r, int ch) {
  return (r << 6) + (((ch ^ (r & 7)) & 7) << 3);
}

// DPP-based max step over the 16-lane DPP row (VALU pipe, not LDS pipe).
template <int CTRL>
static __device__ __forceinline__ float fmax_dpp(float t) {
  int m = __builtin_amdgcn_mov_dpp(__builtin_bit_cast(int, t), CTRL, 0xF, 0xF, true);
  return fmaxf(t, __builtin_bit_cast(float, m));
}

// ---------------------------------------------------------------------------
// Fused attention, 32-rows/wave + KV-split.  256 blocks x 512 threads.
// bid: h = bid&7 (XCD); s = bid>>3: qt = s&3 (256-row q-tile), b = (s>>2)&3,
// kvh = s>>4.  Wave w owns q-rows [qt*256 + w*32, +32) as 2 row-groups of 16.
// Block processes kv-tiles [kvh*8, kvh*8+8); emits partial (O, m, l).
// Shared LDS: k/vt tiles + one 320-row rk band (all waves/groups).
// ---------------------------------------------------------------------------
__global__ __launch_bounds__(512) void fused_attn_kernel(
    const u16* __restrict__ qc, const u16* __restrict__ qr,
    const u16* __restrict__ kb, const u16* __restrict__ vt,
    const u16* __restrict__ rk,
    float* __restrict__ opart, f32x2* __restrict__ mlpart)
{
  __shared__ __align__(16) u16 kbLds[64 * 64];       // 8KB   k tile [j][d]
  __shared__ __align__(16) u16 vtLds[64 * 64];       // 8KB   vt tile [c][j]
  __shared__ __align__(16) u16 rkLds[320 * 64];      // 40KB  shared rk band
  __shared__ __align__(16) u16 pLds[8][2][16 * 64];  // 32KB  per-wave/rg P

  const int tid  = threadIdx.x;
  const int lane = tid & 63;
  const int w    = tid >> 6;          // 0..7
  const int g    = lane >> 4;
  const int li   = lane & 15;

  const int bid = blockIdx.x;         // XCD = bid&7 = h
  const int h   = bid & 7;
  const int s   = bid >> 3;
  const int qt  = s & 3;
  const int b   = (s >> 2) & 3;
  const int kvh = s >> 4;
  const int t0  = qt * 256;

  // Q fragments for both row-groups (row = t0 + w*32 + rg*16 + li)
  const int64_t qbase = (int64_t)b * 524288 + h * 64 + g * 8;
  bf16x8 qcf[2][2], qrf[2][2];
#pragma unroll
  for (int rg = 0; rg < 2; ++rg) {
    const int64_t ro = qbase + (int64_t)(t0 + w * 32 + rg * 16 + li) * 512;
    qcf[rg][0] = *(const bf16x8*)(qc + ro);
    qcf[rg][1] = *(const bf16x8*)(qc + ro + 32);
    qrf[rg][0] = *(const bf16x8*)(qr + ro);
    qrf[rg][1] = *(const bf16x8*)(qr + ro + 32);
  }

  const u16* kbB = kb + (int64_t)b * 524288 + h * 64;
  const u16* vtB = vt + (int64_t)(b * 8 + h) * 65536;
  const u16* rkB = rk + h * 64;

  bf16x8 ones;
#pragma unroll
  for (int e = 0; e < 8; ++e) ((u16*)&ones)[e] = 0x3F80;

  float m_[2][4];
  f32x4 o_[2][4], o4[2];
#pragma unroll
  for (int rg = 0; rg < 2; ++rg) {
    o4[rg] = (f32x4){0.f, 0.f, 0.f, 0.f};
#pragma unroll
    for (int n = 0; n < 4; ++n) {
      o_[rg][n] = (f32x4){0.f, 0.f, 0.f, 0.f};
      m_[rg][n] = -1e30f;
    }
  }

  // band-merge constants (shared by both row-groups)
  const int base = li - 4 * g + 15;            // in [3,30]
  int  srcj[4];
  bool cndj[4];
#pragma unroll
  for (int j = 0; j < 4; ++j) {
    srcj[j] = ((base - j) & 15) | (lane & 48);
    cndj[j] = (base - j) < 16;
  }
  const int bandRow0 = 224 - 32 * w;           // rg1 frag base; rg0 = +16

  // staging regs: k/vt 1 chunk/thread, band 5 chunks/thread (320 rows)
  u16x8 sk, svv, srr[5];
  auto ISSUE = [&](int itx) {
    const int j0 = itx * 64;
    const int r = tid >> 3, ch = tid & 7;
    sk  = *(const u16x8*)(kbB + (int64_t)(j0 + r) * 512 + ch * 8);
    svv = *(const u16x8*)(vtB + (int64_t)r * 1024 + j0 + ch * 8);
    const int ubB = 1024 + j0 - t0 - 255;      // >= 1
#pragma unroll
    for (int p = 0; p < 5; ++p) {
      const int flat = p * 512 + tid, r2 = flat >> 3, ch2 = flat & 7;
      int u = ubB + r2; u = u < 2047 ? u : 2047;
      srr[p] = *(const u16x8*)(rkB + (int64_t)u * 512 + ch2 * 8);
    }
  };

  const int it0 = kvh * 8, it1 = it0 + 8;
  ISSUE(it0);
  for (int it = it0; it < it1; ++it) {
    __syncthreads();   // prev compute's LDS reads done
    {
      const int r = tid >> 3, ch = tid & 7;
      *(u16x8*)&kbLds[swzIdx(r, ch)] = sk;
      *(u16x8*)&vtLds[swzIdx(r, ch)] = svv;
#pragma unroll
      for (int p = 0; p < 5; ++p) {
        const int flat = p * 512 + tid, r2 = flat >> 3, ch2 = flat & 7;
        *(u16x8*)&rkLds[swzIdx(r2, ch2)] = srr[p];
      }
    }
    __syncthreads();   // tile visible
    if (it + 1 < it1) ISSUE(it + 1);   // flies under compute

    // ---- content logits (B-frag shared by both row-groups) ----
    f32x4 c_[2][4];
#pragma unroll
    for (int rg = 0; rg < 2; ++rg)
#pragma unroll
      for (int n = 0; n < 4; ++n) c_[rg][n] = (f32x4){0.f, 0.f, 0.f, 0.f};
#pragma unroll
    for (int kc = 0; kc < 2; ++kc) {
      const int chn = kc * 4 + g;
#pragma unroll
      for (int n = 0; n < 4; ++n) {
        bf16x8 bb = *(const bf16x8*)&kbLds[swzIdx(n * 16 + li, chn)];
        c_[0][n] = __builtin_amdgcn_mfma_f32_16x16x32_bf16(qcf[0][kc], bb, c_[0][n], 0, 0, 0);
        c_[1][n] = __builtin_amdgcn_mfma_f32_16x16x32_bf16(qcf[1][kc], bb, c_[1][n], 0, 0, 0);
      }
    }
    // ---- rel band: 6 shared frags feed both row-groups (rg0: k-1, rg1: k) --
    f32x4 r_[2][5];
#pragma unroll
    for (int rg = 0; rg < 2; ++rg)
#pragma unroll
      for (int f = 0; f < 5; ++f) r_[rg][f] = (f32x4){0.f, 0.f, 0.f, 0.f};
#pragma unroll
    for (int kc = 0; kc < 2; ++kc) {
      const int chn = kc * 4 + g;
#pragma unroll
      for (int k = 0; k < 6; ++k) {
        bf16x8 bb = *(const bf16x8*)&rkLds[swzIdx(bandRow0 + k * 16 + li, chn)];
        if (k >= 1)
          r_[0][k - 1] = __builtin_amdgcn_mfma_f32_16x16x32_bf16(qrf[0][kc], bb, r_[0][k - 1], 0, 0, 0);
        if (k < 5)
          r_[1][k]     = __builtin_amdgcn_mfma_f32_16x16x32_bf16(qrf[1][kc], bb, r_[1][k], 0, 0, 0);
      }
    }
    // ---- band merge (per row-group; srcj/cndj shared) ----
    float sv2[2][4][4];
#pragma unroll
    for (int rg = 0; rg < 2; ++rg) {
      float vsh[5][4];
#pragma unroll
      for (int f = 0; f < 5; ++f)
#pragma unroll
        for (int j = 0; j < 4; ++j)
          vsh[f][j] = __shfl(r_[rg][f][j], srcj[j], 64);
#pragma unroll
      for (int n = 0; n < 4; ++n)
#pragma unroll
        for (int j = 0; j < 4; ++j)
          sv2[rg][n][j] = c_[rg][n][j] + (cndj[j] ? vsh[n][j] : vsh[n + 1][j]);
    }

    // ---- online softmax: DPP max + combined exact defer-rescale ----
    float tmax[2][4];
    bool grow = false;
#pragma unroll
    for (int rg = 0; rg < 2; ++rg)
#pragma unroll
      for (int j = 0; j < 4; ++j) {
        float t = fmaxf(fmaxf(sv2[rg][0][j], sv2[rg][1][j]),
                        fmaxf(sv2[rg][2][j], sv2[rg][3][j]));
        t = fmax_dpp<0xB1>(t);    // quad_perm [1,0,3,2]
        t = fmax_dpp<0x4E>(t);    // quad_perm [2,3,0,1]
        t = fmax_dpp<0x124>(t);   // row_ror:4
        t = fmax_dpp<0x128>(t);   // row_ror:8
        tmax[rg][j] = t;
        grow = grow || (t > m_[rg][j]);
      }
    if (__any(grow)) {
#pragma unroll
      for (int rg = 0; rg < 2; ++rg) {
        float al[4];
#pragma unroll
        for (int j = 0; j < 4; ++j) {
          const float nm = fmaxf(m_[rg][j], tmax[rg][j]);
          al[j] = __expf(m_[rg][j] - nm);     // == 1.0f exactly if not grown
          m_[rg][j] = nm;
        }
#pragma unroll
        for (int n = 0; n < 4; ++n)
#pragma unroll
          for (int j = 0; j < 4; ++j) o_[rg][n][j] *= al[j];
#pragma unroll
        for (int j = 0; j < 4; ++j) o4[rg][j] *= al[j];
      }
    }
#pragma unroll
    for (int rg = 0; rg < 2; ++rg) {
      u16* pw = &pLds[w][rg][0];
#pragma unroll
      for (int n = 0; n < 4; ++n)
#pragma unroll
        for (int j = 0; j < 4; ++j) {
          const float p = __expf(sv2[rg][n][j] - m_[rg][j]);
          const int rw = g * 4 + j, col = n * 16 + li;
          pw[(rw << 6) + ((((col >> 3) ^ (rw & 7)) & 7) << 3) + (col & 7)] = f2bf(p);
        }
    }

    // ---- PV (vb shared by both row-groups; + ones column for l) ----
#pragma unroll
    for (int kc = 0; kc < 2; ++kc) {
      const int chn = kc * 4 + g;
      bf16x8 pa0 = *(const bf16x8*)&pLds[w][0][swzIdx(li, chn)];
      bf16x8 pa1 = *(const bf16x8*)&pLds[w][1][swzIdx(li, chn)];
#pragma unroll
      for (int n = 0; n < 4; ++n) {
        bf16x8 vb = *(const bf16x8*)&vtLds[swzIdx(n * 16 + li, chn)];
        o_[0][n] = __builtin_amdgcn_mfma_f32_16x16x32_bf16(pa0, vb, o_[0][n], 0, 0, 0);
        o_[1][n] = __builtin_amdgcn_mfma_f32_16x16x32_bf16(pa1, vb, o_[1][n], 0, 0, 0);
      }
      o4[0] = __builtin_amdgcn_mfma_f32_16x16x32_bf16(pa0, ones, o4[0], 0, 0, 0);
      o4[1] = __builtin_amdgcn_mfma_f32_16x16x32_bf16(pa1, ones, o4[1], 0, 0, 0);
    }
  }

  // ---- partial epilogue: opart[kvh][b][h][row][c] fp32 (undivided), m/l ----
#pragma unroll
  for (int rg = 0; rg < 2; ++rg) {
    const int trow = t0 + w * 32 + rg * 16;
    float* opB = opart + ((int64_t)kvh * 32 + b * 8 + h) * 65536
               + (int64_t)trow * 64;
#pragma unroll
    for (int n = 0; n < 4; ++n)
#pragma unroll
      for (int j = 0; j < 4; ++j)
        opB[(g * 4 + j) * 64 + n * 16 + li] = o_[rg][n][j];
    if (li == 0) {
#pragma unroll
      for (int j = 0; j < 4; ++j)
        mlpart[((int64_t)kvh * 32 + b * 8 + h) * 1024 + trow + g * 4 + j] =
            (f32x2){m_[rg][j], o4[rg][j]};
    }
  }
}

// merge the two kv-half partials -> ob (bf16).  4 rows/block, grid 8192.
__global__ __launch_bounds__(256) void attn_merge(
    const float* __restrict__ opart, const f32x2* __restrict__ mlpart,
    u16* __restrict__ ob)
{
  const int rid = blockIdx.x * 4 + (threadIdx.x >> 6);   // [0, 32768)
  const int lane = threadIdx.x & 63;
  const f32x2 ml1 = mlpart[rid];
  const f32x2 ml2 = mlpart[32768 + rid];
  const float m  = fmaxf(ml1[0], ml2[0]);
  const float a1 = __expf(ml1[0] - m), a2 = __expf(ml2[0] - m);
  const float inv = 1.f / (ml1[1] * a1 + ml2[1] * a2);
  const float o1 = opart[(int64_t)rid * 64 + lane];
  const float o2 = opart[2097152 + (int64_t)rid * 64 + lane];
  const int b = rid >> 13, h = (rid >> 10) & 7, t = rid & 1023;
  ob[(int64_t)b * 524288 + (int64_t)t * 512 + h * 64 + lane] =
      f2bf((o1 * a1 + o2 * a2) * inv);
}

enum { EPI_BF16 = 0, EPI_BF16_RELU = 1, EPI_F32 = 2 };

// C[m,n] = sum_k A[m,k] * Bt[n,k].  Tile 128 x (NW*32).  gld_lds staging,
// double-buffered 2-phase.
template <int EPI, int NW>
__global__ __launch_bounds__(256) void gemm_bt(
    const u16* __restrict__ A, int64_t zA, int lda,
    const u16* __restrict__ Bt, int64_t zB, int ldb,
    char* __restrict__ Cb, int64_t zCbytes, int ldc,
    const float* __restrict__ bias1, int zbias,
    int M, int N, int K)
{
  __shared__ __align__(16) u16 As[2][128 * BK];
  __shared__ __align__(16) u16 Bs[2][NW * 32 * BK];

  const int z = blockIdx.z;
  A  += (int64_t)z * zA;
  Bt += (int64_t)z * zB;
  Cb += (int64_t)z * zCbytes;

  const int m0 = blockIdx.y * 128;
  const int n0 = blockIdx.x * (NW * 32);

  const int tid  = threadIdx.x;
  const int lane = tid & 63;
  const int wid  = tid >> 6;
  const int wm = (wid >> 1) * 64;
  const int wn = (wid & 1) * (NW * 16);
  const int fr = lane & 15;
  const int fk = (lane >> 4) * 8;

  f32x4 acc[4][NW];
#pragma unroll
  for (int m = 0; m < 4; ++m)
#pragma unroll
    for (int n = 0; n < NW; ++n) acc[m][n] = (f32x4){0.f, 0.f, 0.f, 0.f};

  const int nsteps = K >> 6;
  auto STAGE = [&](int step, int buf) {
    const int kt = step * BK;
#pragma unroll
    for (int it = 0; it < 4; ++it) {
      const int off = (it * 256 + tid) * 8;
      const int r = off >> 6, c = off & (BK - 1);
      int gr = m0 + r; if (gr > M - 1) gr = M - 1;
      gld16(A + (int64_t)gr * lda + kt + c, &As[buf][off]);
    }
#pragma unroll
    for (int it = 0; it < NW; ++it) {
      const int off = (it * 256 + tid) * 8;
      const int r = off >> 6, c = off & (BK - 1);
      int gr = n0 + r; if (gr > N - 1) gr = N - 1;
      gld16(Bt + (int64_t)gr * ldb + kt + c, &Bs[buf][off]);
    }
  };

  STAGE(0, 0);
  for (int s = 0; s < nsteps; ++s) {
    const int cur = s & 1;
    __syncthreads();
    if (s + 1 < nsteps) STAGE(s + 1, cur ^ 1);

#pragma unroll
    for (int kk = 0; kk < BK; kk += 32) {
      bf16x8 af[4], bfv[NW];
#pragma unroll
      for (int m = 0; m < 4; ++m)
        af[m] = *(const bf16x8*)&As[cur][(wm + m * 16 + fr) * BK + kk + fk];
#pragma unroll
      for (int n = 0; n < NW; ++n)
        bfv[n] = *(const bf16x8*)&Bs[cur][(wn + n * 16 + fr) * BK + kk + fk];
#pragma unroll
      for (int m = 0; m < 4; ++m)
#pragma unroll
        for (int n = 0; n < NW; ++n)
          acc[m][n] = __builtin_amdgcn_mfma_f32_16x16x32_bf16(af[m], bfv[n], acc[m][n], 0, 0, 0);
    }
  }

  const int r0 = m0 + wm + (lane >> 4) * 4;
  const int c0 = n0 + wn + fr;
#pragma unroll
  for (int m = 0; m < 4; ++m) {
#pragma unroll
    for (int n = 0; n < NW; ++n) {
      const int col = c0 + n * 16;
      if (col >= N) continue;
      float b1v = 0.f;
      if (EPI == EPI_BF16 || EPI == EPI_BF16_RELU) {
        if (bias1) b1v = bias1[z * zbias + col];
      }
#pragma unroll
      for (int j = 0; j < 4; ++j) {
        const int row = r0 + m * 16 + j;
        if (row >= M) continue;
        const float v = acc[m][n][j];
        if (EPI == EPI_BF16) {
          ((u16*)Cb)[(int64_t)row * ldc + col] = f2bf(v + b1v);
        } else if (EPI == EPI_BF16_RELU) {
          float t = v + b1v; t = t > 0.f ? t : 0.f;
          ((u16*)Cb)[(int64_t)row * ldc + col] = f2bf(t);
        } else if (EPI == EPI_F32) {
          ((float*)Cb)[(int64_t)row * ldc + col] = v;
        }
      }
    }
  }
}

// Merged QKV + rk projection.  896 blocks: [0,768) QKV (N=1536 over
// WqT|WkT|WvT, M=4096), [768,896) rk = pe@WrT (M=2048, N=512).  NW=2.
// V columns (which==2) are written DIRECTLY to vt (b,h,dh,l) as u16x4.
__global__ __launch_bounds__(256) void gemm_qkv_rk(
    const u16* __restrict__ xb, const u16* __restrict__ pe,
    const u16* __restrict__ WqkvT, const u16* __restrict__ WrT,
    char* __restrict__ qcBase, u16* __restrict__ vtOut,
    u16* __restrict__ rkOut, const float* __restrict__ biasAll)
{
  __shared__ __align__(16) u16 As[2][128 * BK];
  __shared__ __align__(16) u16 Bs[2][64 * BK];

  const bool isRk = blockIdx.x >= 768;
  const int bidl = isRk ? (blockIdx.x - 768) : blockIdx.x;
  const int m0 = isRk ? (bidl >> 3) * 128 : (bidl / 24) * 128;
  const int n0 = isRk ? (bidl & 7) * 64   : (bidl % 24) * 64;
  const u16* A  = isRk ? pe   : xb;
  const u16* Bt = isRk ? WrT  : WqkvT;

  const int tid  = threadIdx.x;
  const int lane = tid & 63;
  const int wid  = tid >> 6;
  const int wm = (wid >> 1) * 64;
  const int wn = (wid & 1) * 32;
  const int fr = lane & 15;
  const int fk = (lane >> 4) * 8;

  f32x4 acc[4][2];
#pragma unroll
  for (int m = 0; m < 4; ++m)
#pragma unroll
    for (int n = 0; n < 2; ++n) acc[m][n] = (f32x4){0.f, 0.f, 0.f, 0.f};

  auto STAGE = [&](int step, int buf) {
    const int kt = step * BK;
#pragma unroll
    for (int it = 0; it < 4; ++it) {
      const int off = (it * 256 + tid) * 8;
      const int r = off >> 6, c = off & (BK - 1);
      gld16(A + (int64_t)(m0 + r) * 512 + kt + c, &As[buf][off]);
    }
#pragma unroll
    for (int it = 0; it < 2; ++it) {
      const int off = (it * 256 + tid) * 8;
      const int r = off >> 6, c = off & (BK - 1);
      gld16(Bt + (int64_t)(n0 + r) * 512 + kt + c, &Bs[buf][off]);
    }
  };

  STAGE(0, 0);
  for (int s = 0; s < 8; ++s) {      // K = 512
    const int cur = s & 1;
    __syncthreads();
    if (s + 1 < 8) STAGE(s + 1, cur ^ 1);

#pragma unroll
    for (int kk = 0; kk < BK; kk += 32) {
      bf16x8 af[4], bfv[2];
#pragma unroll
      for (int m = 0; m < 4; ++m)
        af[m] = *(const bf16x8*)&As[cur][(wm + m * 16 + fr) * BK + kk + fk];
#pragma unroll
      for (int n = 0; n < 2; ++n)
        bfv[n] = *(const bf16x8*)&Bs[cur][(wn + n * 16 + fr) * BK + kk + fk];
#pragma unroll
      for (int m = 0; m < 4; ++m)
#pragma unroll
        for (int n = 0; n < 2; ++n)
          acc[m][n] = __builtin_amdgcn_mfma_f32_16x16x32_bf16(af[m], bfv[n], acc[m][n], 0, 0, 0);
    }
  }

  const int r0 = m0 + wm + (lane >> 4) * 4;
  const int c0 = n0 + wn + fr;
#pragma unroll
  for (int m = 0; m < 4; ++m) {
#pragma unroll
    for (int n = 0; n < 2; ++n) {
      const int col = c0 + n * 16;
      if (isRk) {
#pragma unroll
        for (int j = 0; j < 4; ++j)
          rkOut[(int64_t)(r0 + m * 16 + j) * 512 + col] = f2bf(acc[m][n][j]);
      } else {
        const int which = col >> 9, cc = col & 511;
        if (which == 2) {
          u16x4 pv;
          const float bv = biasAll[1536 + cc];
#pragma unroll
          for (int j = 0; j < 4; ++j) pv[j] = f2bf(acc[m][n][j] + bv);
          const int row0 = r0 + m * 16;
          const int bb = row0 >> 10, t = row0 & 1023;
          *(u16x4*)&vtOut[(int64_t)(bb * 8 + (cc >> 6)) * 65536
                          + (cc & 63) * 1024 + t] = pv;
        } else {
          const int slot = (which == 0) ? 0 : 2;   // 0:qc(+qr) 2:kb
#pragma unroll
          for (int j = 0; j < 4; ++j) {
            const int row = r0 + m * 16 + j;
            const float v = acc[m][n][j];
            u16* dst = (u16*)qcBase + (int64_t)slot * 2097152
                     + (int64_t)row * 512 + cc;
            *dst = f2bf(v + biasAll[slot * 512 + cc]);
            if (which == 0)                        // slot 1: qr
              dst[2097152] = f2bf(v + biasAll[512 + cc]);
          }
        }
      }
    }
  }
}

// ---------------------------------------------------------------------------
// ALL preprocessing in one dispatch (9474 blocks).
// ---------------------------------------------------------------------------
__global__ __launch_bounds__(256) void prep_all(
    const float* __restrict__ x,
    const float* __restrict__ Wq, const float* __restrict__ Wk,
    const float* __restrict__ Wv, const float* __restrict__ Wo,
    const float* __restrict__ Wr, const float* __restrict__ W1,
    const float* __restrict__ W2,
    const float* __restrict__ bq, const float* __restrict__ cb,
    const float* __restrict__ rb, const float* __restrict__ bk,
    const float* __restrict__ bv, char* __restrict__ wsb)
{
  __shared__ float t[32][33];
  const int bid = blockIdx.x;
  const int tid = threadIdx.x;
  if (bid < 4096) {                       // pe
    u16* pe = (u16*)(wsb + 20480);
    int idx = bid * 256 + tid;
    int i = idx >> 9, j = idx & 511, jf = j & 255;
    float inv = __expf(-(float)jf * (2.0f / 512.0f) * 9.210340371976184f);
    float arg = (float)(i - 1024) * inv;
    pe[idx] = f2bf((j < 256) ? __sinf(arg) : __cosf(arg));
  } else if (bid < 6144) {                // convert x
    u16* xb = (u16*)(wsb + 8933376);
    int idx = (bid - 4096) * 256 + tid;
    f32x4 v = ((const f32x4*)x)[idx];
    u16x4 o;
    o[0] = f2bf(v[0]); o[1] = f2bf(v[1]); o[2] = f2bf(v[2]); o[3] = f2bf(v[3]);
    ((u16x4*)xb)[idx] = o;
  } else if (bid < 6146) {                // biases (bqc|bqr|bkv contiguous)
    int i = (bid - 6144) * 256 + tid;
    float* bqc = (float*)wsb;
    if (i < 512) {
      bqc[i]        = bq[i] + cb[i];
      bqc[512 + i]  = bq[i] + rb[i];
      bqc[1024 + i] = bk[i];
      bqc[1536 + i] = bv[i];
    }
  } else {                                // transposes
    const int tl0 = bid - 6146;
    const float* src; u16* dst;
    int ldi, ldo, bx, by;
    if (tl0 < 1280) {
      const int wsel = tl0 >> 8, tl = tl0 & 255;
      bx = tl & 15; by = tl >> 4; ldi = 512; ldo = 512;
      src = (wsel == 0) ? Wq : (wsel == 1) ? Wk : (wsel == 2) ? Wv
          : (wsel == 3) ? Wo : Wr;
      dst = (u16*)(wsb + 2117632 + (int64_t)wsel * 524288);
    } else if (tl0 < 2304) {
      const int tl = tl0 - 1280;
      bx = tl & 63; by = tl >> 6; ldi = 2048; ldo = 512;
      src = W1; dst = (u16*)(wsb + 4739072);
    } else {
      const int tl = tl0 - 2304;
      bx = tl & 15; by = tl >> 4; ldi = 512; ldo = 2048;
      src = W2; dst = (u16*)(wsb + 6836224);
    }
    const int xx = tid & 31, yy = tid >> 5;   // 32 x 8
    const int r0 = by * 32, c0 = bx * 32;
#pragma unroll
    for (int i = 0; i < 32; i += 8)
      t[yy + i][xx] = src[(int64_t)(r0 + yy + i) * ldi + c0 + xx];
    __syncthreads();
#pragma unroll
    for (int i = 0; i < 32; i += 8)
      dst[(int64_t)(c0 + yy + i) * ldo + r0 + xx] = f2bf(t[xx][yy + i]);
  }
}

// LN over val = 2*(X1 + X2 + bias).  one wave/row, 4 rows/block, grid(1024).
template <int OUT_F32>
__global__ void layernorm_sum2_kernel(
    const float* __restrict__ X1, const float* __restrict__ X2,
    const float* __restrict__ bias,
    const float* __restrict__ sc, const float* __restrict__ bi,
    void* __restrict__ outv) {
  const int row = blockIdx.x * 4 + (threadIdx.x >> 6);
  const int lane = threadIdx.x & 63;
  const int64_t ro = (int64_t)row * 512;
  f32x4 a1 = ((const f32x4*)(X1 + ro))[lane];
  f32x4 a2 = ((const f32x4*)(X1 + ro))[lane + 64];
  f32x4 b1 = ((const f32x4*)(X2 + ro))[lane];
  f32x4 b2 = ((const f32x4*)(X2 + ro))[lane + 64];
  f32x4 c1 = ((const f32x4*)bias)[lane];
  f32x4 c2 = ((const f32x4*)bias)[lane + 64];
  f32x4 a, b;
#pragma unroll
  for (int e = 0; e < 4; ++e) {
    a[e] = 2.f * (a1[e] + b1[e] + c1[e]);
    b[e] = 2.f * (a2[e] + b2[e] + c2[e]);
  }
  float s = 0.f, q = 0.f;
#pragma unroll
  for (int e = 0; e < 4; ++e) { s += a[e] + b[e]; q += a[e]*a[e] + b[e]*b[e]; }
#pragma unroll
  for (int o = 32; o; o >>= 1) { s += __shfl_xor(s, o, 64); q += __shfl_xor(q, o, 64); }
  const float mu = s * (1.f / 512.f);
  const float var = q * (1.f / 512.f) - mu * mu;
  const float r = rsqrtf(var + 1e-6f);
  const int cc1 = lane * 4, cc2 = (lane + 64) * 4;
  f32x4 s1 = ((const f32x4*)sc)[lane], s2 = ((const f32x4*)sc)[lane + 64];
  f32x4 g1 = ((const f32x4*)bi)[lane], g2 = ((const f32x4*)bi)[lane + 64];
  if (OUT_F32) {
    float* out = (float*)outv;
    f32x4 o1, o2;
#pragma unroll
    for (int e = 0; e < 4; ++e) {
      o1[e] = (a[e] - mu) * r * s1[e] + g1[e];
      o2[e] = (b[e] - mu) * r * s2[e] + g2[e];
    }
    *(f32x4*)&out[ro + cc1] = o1;
    *(f32x4*)&out[ro + cc2] = o2;
  } else {
    u16* out = (u16*)outv;
    u16x4 o1, o2;
#pragma unroll
    for (int e = 0; e < 4; ++e) {
      o1[e] = f2bf((a[e] - mu) * r * s1[e] + g1[e]);
      o2[e] = f2bf((b[e] - mu) * r * s2[e] + g2[e]);
    }
    *(u16x4*)&out[ro + cc1] = o1;
    *(u16x4*)&out[ro + cc2] = o2;
  }
}

// ---------------------------------------------------------------------------
extern "C" void kernel_launch(void* const* d_in, const int* in_sizes, int n_in,
                              void* d_out, int out_size, void* d_ws, size_t ws_size,
                              hipStream_t stream) {
  const float* x    = (const float*)d_in[0];
  const float* Wq   = (const float*)d_in[1];
  const float* bq   = (const float*)d_in[2];
  const float* Wk   = (const float*)d_in[3];
  const float* bk   = (const float*)d_in[4];
  const float* Wv   = (const float*)d_in[5];
  const float* bv   = (const float*)d_in[6];
  const float* cb   = (const float*)d_in[7];
  const float* rb   = (const float*)d_in[8];
  const float* Wr   = (const float*)d_in[9];
  const float* Wo   = (const float*)d_in[10];
  const float* bo   = (const float*)d_in[11];
  const float* ln1s = (const float*)d_in[12];
  const float* ln1b = (const float*)d_in[13];
  const float* W1   = (const float*)d_in[14];
  const float* b1   = (const float*)d_in[15];
  const float* W2   = (const float*)d_in[16];
  const float* b2   = (const float*)d_in[17];
  const float* ln2s = (const float*)d_in[18];
  const float* ln2b = (const float*)d_in[19];
  (void)in_sizes; (void)n_in; (void)out_size; (void)ws_size;

  char* ws = (char*)d_ws;
  float* bqc = (float*)(ws + 0);          // bqc|bqr|bkv contiguous (2048 f32)
  u16* pe  = (u16*)(ws + 20480);          // 2048x512 bf16
  u16* WqT = (u16*)(ws + 2117632);        // Wq|Wk|Wv T contiguous (1536x512)
  u16* WoT = (u16*)(ws + 3690496);
  u16* WrT = (u16*)(ws + 4214784);
  u16* W1T = (u16*)(ws + 4739072);        // 2048x512
  u16* W2T = (u16*)(ws + 6836224);        // 512x2048
  u16* xb  = (u16*)(ws + 8933376);        // 4096x512 bf16
  u16* qc  = (u16*)(ws + 13127680);       // qc|qr|kb slots (+2097152 u16 each)
  u16* kb  = (u16*)(ws + 21516288);
  u16* vt  = (u16*)(ws + 29904896);       // (b,h,dh,l) written by QKV epilogue
  u16* rk  = (u16*)(ws + 34099200);       // 2048x512
  u16* ob  = (u16*)(ws + 36196352);       // 4096x512 (attn out)
  char* scratch = ws + 40390656;
  // attn partials (live only between attn and merge):
  float* opart  = (float*)scratch;                 // [2][4][8][1024][64] 16MB
  f32x2* mlpart = (f32x2*)(scratch + 16777216);    // [2][4][8][1024] 512KB
  // post-merge reuse:
  float* pA  = (float*)scratch;                   // 4096x512 fp32
  float* pB  = (float*)(ws + 13127680);           // qc region (dead post-attn)
  u16*   ln1 = (u16*)(scratch + 8388608);         // 4096x512 bf16
  u16*   ffn1= (u16*)(scratch + 12582912);        // 4096x2048 bf16
  const int64_t zPart = (int64_t)((char*)pB - (char*)pA);

  const dim3 blk(256);

  prep_all<<<dim3(9474), blk, 0, stream>>>(x, Wq, Wk, Wv, Wo, Wr, W1, W2,
                                           bq, cb, rb, bk, bv, ws);

  // fused q/qr/k/v projection (v -> vt directly) + rk projection
  gemm_qkv_rk<<<dim3(896), blk, 0, stream>>>(xb, pe, WqT, WrT,
                                             (char*)qc, vt, rk, bqc);

  // fused attention, 32 rows/wave + kv-split (256 blocks x 512 threads)
  fused_attn_kernel<<<dim3(256), dim3(512), 0, stream>>>(
      qc, qc + 2097152, kb, vt, rk, opart, mlpart);
  attn_merge<<<dim3(8192), blk, 0, stream>>>(opart, mlpart, ob);

  // o@Wo, K-split z=2 -> partials; LN1 folds +bo, x2, sum
  gemm_bt<EPI_F32, 2><<<dim3(8, 32, 2), blk, 0, stream>>>(
      ob, 256, 512, WoT, 256, 512, (char*)pA, zPart, 512, nullptr, 0,
      4096, 512, 256);
  layernorm_sum2_kernel<0><<<dim3(1024), blk, 0, stream>>>(
      pA, pB, bo, ln1s, ln1b, ln1);
  // FFN
  gemm_bt<EPI_BF16_RELU, 4><<<dim3(16, 32, 1), blk, 0, stream>>>(
      ln1, 0, 512, W1T, 0, 512, (char*)ffn1, 0, 2048, b1, 0, 4096, 2048, 512);
  gemm_bt<EPI_F32, 2><<<dim3(8, 32, 2), blk, 0, stream>>>(
      ffn1, 1024, 2048, W2T, 1024, 2048, (char*)pA, zPart, 512, nullptr, 0,
      4096, 512, 1024);
  layernorm_sum2_kernel<1><<<dim3(1024), blk, 0, stream>>>(
      pA, pB, b2, ln2s, ln2b, d_out);
}

// Round 15
// 137.762 us; speedup vs baseline: 1.0338x; 1.0338x over previous
//
#include <hip/hip_runtime.h>
#include <stdint.h>

// ---------------------------------------------------------------------------
// TransformerXL encoder layer.  Inputs fp32, OUTPUT fp32.  b=4 l=1024 d=512
// h=8 dh=64.
// Round 15: revert round-14 (kv-split tax > intensity gain; 2nd confirmation).
// Base = round 13 (best known, 136.0us).  Single change: T5 s_setprio(1)
// around attn MFMA clusters (m191: +4-7% attn; waves de-phase after barrier
// -> scheduler can prefer MFMA-issuing waves).
// rel shift closed form: shifted[t,j] = R[t, 1024 + j - t],  R = (q+rb)@rk^T.
// ---------------------------------------------------------------------------

typedef unsigned short u16;
typedef __attribute__((ext_vector_type(8))) __bf16 bf16x8;
typedef __attribute__((ext_vector_type(8))) unsigned short u16x8;
typedef __attribute__((ext_vector_type(4))) float f32x4;
typedef __attribute__((ext_vector_type(4))) unsigned short u16x4;

#define BK 64

static __device__ __forceinline__ u16 f2bf(float f) {
  union { float f; unsigned int i; } v; v.f = f;
  unsigned int r = v.i + 0x7FFFu + ((v.i >> 16) & 1u);
  return (u16)(r >> 16);
}

// global->LDS direct copy, 16B per lane (lds dest must be linear in lane id).
static __device__ __forceinline__ void gld16(const void* g, void* l) {
  __builtin_amdgcn_global_load_lds(
      (__attribute__((address_space(1))) void*)(uintptr_t)g,
      (__attribute__((address_space(3))) void*)(uintptr_t)l,
      16, 0, 0);
}

// swizzled u16 index into a [rows][64]-u16 LDS tile (16B chunk ^= row&7).
static __device__ __forceinline__ int swzIdx(int r, int ch) {
  return (r << 6) + (((ch ^ (r & 7)) & 7) << 3);
}

// DPP-based max step over the 16-lane DPP row (VALU pipe, not LDS pipe).
template <int CTRL>
static __device__ __forceinline__ float fmax_dpp(float t) {
  int m = __builtin_amdgcn_mov_dpp(__builtin_bit_cast(int, t), CTRL, 0xF, 0xF, true);
  return fmaxf(t, __builtin_bit_cast(float, m));
}

// ---------------------------------------------------------------------------
// Fused attention.  256 blocks x 512 threads.  bid: h = bid&7 (XCD), s=bid>>3:
// qt = s&7, b = s>>3.  Waves 0-3 own q-rows [qt*128, +64), waves 4-7 the next
// 64.  Both halves consume the SAME kv tile -> kb/vt LDS shared.
// Double-buffered kb/vt/rk: one barrier per tile; WRITE(t+1) overlaps
// COMPUTE(t); ISSUE(t+2) gives loads a full iteration to land.
// T5: setprio(1) around the two MFMA clusters.
// ---------------------------------------------------------------------------
__global__ __launch_bounds__(512) void fused_attn_kernel(
    const u16* __restrict__ qc, const u16* __restrict__ qr,
    const u16* __restrict__ kb, const u16* __restrict__ vt,
    const u16* __restrict__ rk, u16* __restrict__ ob)
{
  __shared__ __align__(16) u16 kbLds[2][64 * 64];      // k tile  [j][d]
  __shared__ __align__(16) u16 vtLds[2][64 * 64];      // vt tile [c][j]
  __shared__ __align__(16) u16 rkLds[2][2][128 * 64];  // [buf][half] rk band
  __shared__ __align__(16) u16 pLds[8][16 * 64];       // per-wave P

  const int tid  = threadIdx.x;
  const int lane = tid & 63;
  const int w    = tid >> 6;          // 0..7
  const int th   = w >> 2;            // q-tile half
  const int wl   = w & 3;             // wave within half
  const int g    = lane >> 4;
  const int li   = lane & 15;

  const int bid = blockIdx.x;         // XCD = bid&7 = h
  const int h   = bid & 7;
  const int s   = bid >> 3;
  const int qt  = s & 7;
  const int b   = s >> 3;
  const int t0  = qt * 128 + th * 64; // this half's q-tile base

  const int64_t qoff = (int64_t)b * 524288 + (int64_t)(t0 + wl * 16 + li) * 512
                     + h * 64 + g * 8;
  bf16x8 qcf[2], qrf[2];
  qcf[0] = *(const bf16x8*)(qc + qoff);
  qcf[1] = *(const bf16x8*)(qc + qoff + 32);
  qrf[0] = *(const bf16x8*)(qr + qoff);
  qrf[1] = *(const bf16x8*)(qr + qoff + 32);

  const u16* kbB = kb + (int64_t)b * 524288 + h * 64;
  const u16* vtB = vt + (int64_t)(b * 8 + h) * 65536;
  const u16* rkB = rk + h * 64;

  bf16x8 ones;
#pragma unroll
  for (int e = 0; e < 8; ++e) ((u16*)&ones)[e] = 0x3F80;

  float m_[4] = {-1e30f, -1e30f, -1e30f, -1e30f};
  f32x4 o_[4];
  f32x4 o4 = (f32x4){0.f, 0.f, 0.f, 0.f};        // row-sum accumulator (= l)
#pragma unroll
  for (int n = 0; n < 4; ++n) o_[n] = (f32x4){0.f, 0.f, 0.f, 0.f};

  const int base = li - 4 * g + 15;            // in [3,30]
  int  srcj[4];
  bool cndj[4];
#pragma unroll
  for (int j = 0; j < 4; ++j) {
    srcj[j] = ((base - j) & 15) | (lane & 48);
    cndj[j] = (base - j) < 16;
  }

  const int bhalf = tid >> 8;
  const int tid2  = tid & 255;

  // two static staging reg sets (rule #20: no runtime indexing)
  u16x8 skA, svA, srA[4], skB, svB, srB[4];

  auto ISSUE = [&](int itx, u16x8& skR, u16x8& svR, u16x8* srR) {
    const int j0 = itx * 64;
    const int r = tid >> 3, ch = tid & 7;
    skR = *(const u16x8*)(kbB + (int64_t)(j0 + r) * 512 + ch * 8);
    svR = *(const u16x8*)(vtB + (int64_t)r * 1024 + j0 + ch * 8);
    const int ub = 1024 + j0 - (qt * 128 + bhalf * 64) - 63;   // >= 1
#pragma unroll
    for (int p = 0; p < 4; ++p) {
      const int flat = p * 256 + tid2, r2 = flat >> 3, ch2 = flat & 7;
      int u = ub + r2; u = u < 2047 ? u : 2047;
      srR[p] = *(const u16x8*)(rkB + (int64_t)u * 512 + ch2 * 8);
    }
  };

  auto WRITE = [&](u16* kbL, u16* vtL, u16* rkL,
                   const u16x8& skR, const u16x8& svR, const u16x8* srR) {
    const int r = tid >> 3, ch = tid & 7;
    *(u16x8*)&kbL[swzIdx(r, ch)] = skR;
    *(u16x8*)&vtL[swzIdx(r, ch)] = svR;
#pragma unroll
    for (int p = 0; p < 4; ++p) {
      const int flat = p * 256 + tid2, r2 = flat >> 3, ch2 = flat & 7;
      *(u16x8*)&rkL[bhalf * (128 * 64) + swzIdx(r2, ch2)] = srR[p];
    }
  };

  auto COMPUTE = [&](const u16* kbL, const u16* vtL, const u16* rkL) {
    // ---- content logits + rel band (MFMA cluster 1, T5 boosted) ----
    f32x4 c_[4];
#pragma unroll
    for (int n = 0; n < 4; ++n) c_[n] = (f32x4){0.f, 0.f, 0.f, 0.f};
    f32x4 r_[5];
#pragma unroll
    for (int f = 0; f < 5; ++f) r_[f] = (f32x4){0.f, 0.f, 0.f, 0.f};

    __builtin_amdgcn_s_setprio(1);
#pragma unroll
    for (int kc = 0; kc < 2; ++kc) {
      const int chn = kc * 4 + g;
#pragma unroll
      for (int n = 0; n < 4; ++n) {
        bf16x8 bb = *(const bf16x8*)&kbL[swzIdx(n * 16 + li, chn)];
        c_[n] = __builtin_amdgcn_mfma_f32_16x16x32_bf16(qcf[kc], bb, c_[n], 0, 0, 0);
      }
    }
#pragma unroll
    for (int kc = 0; kc < 2; ++kc) {
      const int chn = kc * 4 + g;
#pragma unroll
      for (int f = 0; f < 5; ++f) {
        const int lr = f * 16 + li + 48 - 16 * wl;
        bf16x8 bb = *(const bf16x8*)&rkL[th * (128 * 64) + swzIdx(lr, chn)];
        r_[f] = __builtin_amdgcn_mfma_f32_16x16x32_bf16(qrf[kc], bb, r_[f], 0, 0, 0);
      }
    }
    __builtin_amdgcn_s_setprio(0);

    // ---- band merge: 20 bpermutes + local select ----
    float vsh[5][4];
#pragma unroll
    for (int f = 0; f < 5; ++f)
#pragma unroll
      for (int j = 0; j < 4; ++j)
        vsh[f][j] = __shfl(r_[f][j], srcj[j], 64);
    float sv2[4][4];
#pragma unroll
    for (int n = 0; n < 4; ++n)
#pragma unroll
      for (int j = 0; j < 4; ++j)
        sv2[n][j] = c_[n][j] + (cndj[j] ? vsh[n][j] : vsh[n + 1][j]);

    // ---- online softmax: DPP max-reduce + exact defer-rescale ----
    float tmax[4];
    bool grow = false;
#pragma unroll
    for (int j = 0; j < 4; ++j) {
      float t = fmaxf(fmaxf(sv2[0][j], sv2[1][j]), fmaxf(sv2[2][j], sv2[3][j]));
      t = fmax_dpp<0xB1>(t);    // quad_perm [1,0,3,2]
      t = fmax_dpp<0x4E>(t);    // quad_perm [2,3,0,1]
      t = fmax_dpp<0x124>(t);   // row_ror:4
      t = fmax_dpp<0x128>(t);   // row_ror:8
      tmax[j] = t;
      grow = grow || (t > m_[j]);
    }
    if (__any(grow)) {
      float al[4];
#pragma unroll
      for (int j = 0; j < 4; ++j) {
        const float nm = fmaxf(m_[j], tmax[j]);
        al[j] = __expf(m_[j] - nm);
        m_[j] = nm;
      }
#pragma unroll
      for (int n = 0; n < 4; ++n)
#pragma unroll
        for (int j = 0; j < 4; ++j) o_[n][j] *= al[j];
#pragma unroll
      for (int j = 0; j < 4; ++j) o4[j] *= al[j];
    }
    u16* pw = pLds[w];
#pragma unroll
    for (int n = 0; n < 4; ++n)
#pragma unroll
      for (int j = 0; j < 4; ++j) {
        const float p = __expf(sv2[n][j] - m_[j]);
        const int rw = g * 4 + j, col = n * 16 + li;
        pw[(rw << 6) + ((((col >> 3) ^ (rw & 7)) & 7) << 3) + (col & 7)] = f2bf(p);
      }

    // ---- PV (+ ones column accumulates l) (MFMA cluster 2, T5 boosted) ----
    __builtin_amdgcn_s_setprio(1);
#pragma unroll
    for (int kc = 0; kc < 2; ++kc) {
      const int chn = kc * 4 + g;
      bf16x8 pa = *(const bf16x8*)&pw[swzIdx(li, chn)];
#pragma unroll
      for (int n = 0; n < 4; ++n) {
        bf16x8 vb = *(const bf16x8*)&vtL[swzIdx(n * 16 + li, chn)];
        o_[n] = __builtin_amdgcn_mfma_f32_16x16x32_bf16(pa, vb, o_[n], 0, 0, 0);
      }
      o4 = __builtin_amdgcn_mfma_f32_16x16x32_bf16(pa, ones, o4, 0, 0, 0);
    }
    __builtin_amdgcn_s_setprio(0);
  };

  // prologue: tile 0 -> buf0, issue tile 1 into set B
  ISSUE(0, skA, svA, srA);
  WRITE(kbLds[0], vtLds[0], &rkLds[0][0][0], skA, svA, srA);
  ISSUE(1, skB, svB, srB);
  __syncthreads();

  for (int ii = 0; ii < 8; ++ii) {
    const int it = ii * 2;
    // even tile: compute buf0; write tile it+1 (set B) -> buf1; issue it+2 -> A
    COMPUTE(kbLds[0], vtLds[0], &rkLds[0][0][0]);
    WRITE(kbLds[1], vtLds[1], &rkLds[1][0][0], skB, svB, srB);
    if (it + 2 < 16) ISSUE(it + 2, skA, svA, srA);
    __syncthreads();
    // odd tile: compute buf1; write tile it+2 (set A) -> buf0; issue it+3 -> B
    COMPUTE(kbLds[1], vtLds[1], &rkLds[1][0][0]);
    if (it + 2 < 16) WRITE(kbLds[0], vtLds[0], &rkLds[0][0][0], skA, svA, srA);
    if (it + 3 < 16) ISSUE(it + 3, skB, svB, srB);
    __syncthreads();
  }

  float inv[4];
#pragma unroll
  for (int j = 0; j < 4; ++j) inv[j] = 1.f / o4[j];
  u16* obB = ob + (int64_t)b * 524288 + (int64_t)(t0 + wl * 16) * 512 + h * 64;
#pragma unroll
  for (int n = 0; n < 4; ++n)
#pragma unroll
    for (int j = 0; j < 4; ++j)
      obB[(int64_t)(g * 4 + j) * 512 + n * 16 + li] = f2bf(o_[n][j] * inv[j]);
}

enum { EPI_BF16 = 0, EPI_BF16_RELU = 1, EPI_F32 = 2 };

// C[m,n] = sum_k A[m,k] * Bt[n,k].  Tile 128 x (NW*32).  gld_lds staging,
// double-buffered 2-phase.
template <int EPI, int NW>
__global__ __launch_bounds__(256) void gemm_bt(
    const u16* __restrict__ A, int64_t zA, int lda,
    const u16* __restrict__ Bt, int64_t zB, int ldb,
    char* __restrict__ Cb, int64_t zCbytes, int ldc,
    const float* __restrict__ bias1, int zbias,
    int M, int N, int K)
{
  __shared__ __align__(16) u16 As[2][128 * BK];
  __shared__ __align__(16) u16 Bs[2][NW * 32 * BK];

  const int z = blockIdx.z;
  A  += (int64_t)z * zA;
  Bt += (int64_t)z * zB;
  Cb += (int64_t)z * zCbytes;

  const int m0 = blockIdx.y * 128;
  const int n0 = blockIdx.x * (NW * 32);

  const int tid  = threadIdx.x;
  const int lane = tid & 63;
  const int wid  = tid >> 6;
  const int wm = (wid >> 1) * 64;
  const int wn = (wid & 1) * (NW * 16);
  const int fr = lane & 15;
  const int fk = (lane >> 4) * 8;

  f32x4 acc[4][NW];
#pragma unroll
  for (int m = 0; m < 4; ++m)
#pragma unroll
    for (int n = 0; n < NW; ++n) acc[m][n] = (f32x4){0.f, 0.f, 0.f, 0.f};

  const int nsteps = K >> 6;
  auto STAGE = [&](int step, int buf) {
    const int kt = step * BK;
#pragma unroll
    for (int it = 0; it < 4; ++it) {
      const int off = (it * 256 + tid) * 8;
      const int r = off >> 6, c = off & (BK - 1);
      int gr = m0 + r; if (gr > M - 1) gr = M - 1;
      gld16(A + (int64_t)gr * lda + kt + c, &As[buf][off]);
    }
#pragma unroll
    for (int it = 0; it < NW; ++it) {
      const int off = (it * 256 + tid) * 8;
      const int r = off >> 6, c = off & (BK - 1);
      int gr = n0 + r; if (gr > N - 1) gr = N - 1;
      gld16(Bt + (int64_t)gr * ldb + kt + c, &Bs[buf][off]);
    }
  };

  STAGE(0, 0);
  for (int s = 0; s < nsteps; ++s) {
    const int cur = s & 1;
    __syncthreads();
    if (s + 1 < nsteps) STAGE(s + 1, cur ^ 1);

#pragma unroll
    for (int kk = 0; kk < BK; kk += 32) {
      bf16x8 af[4], bfv[NW];
#pragma unroll
      for (int m = 0; m < 4; ++m)
        af[m] = *(const bf16x8*)&As[cur][(wm + m * 16 + fr) * BK + kk + fk];
#pragma unroll
      for (int n = 0; n < NW; ++n)
        bfv[n] = *(const bf16x8*)&Bs[cur][(wn + n * 16 + fr) * BK + kk + fk];
#pragma unroll
      for (int m = 0; m < 4; ++m)
#pragma unroll
        for (int n = 0; n < NW; ++n)
          acc[m][n] = __builtin_amdgcn_mfma_f32_16x16x32_bf16(af[m], bfv[n], acc[m][n], 0, 0, 0);
    }
  }

  const int r0 = m0 + wm + (lane >> 4) * 4;
  const int c0 = n0 + wn + fr;
#pragma unroll
  for (int m = 0; m < 4; ++m) {
#pragma unroll
    for (int n = 0; n < NW; ++n) {
      const int col = c0 + n * 16;
      if (col >= N) continue;
      float b1v = 0.f;
      if (EPI == EPI_BF16 || EPI == EPI_BF16_RELU) {
        if (bias1) b1v = bias1[z * zbias + col];
      }
#pragma unroll
      for (int j = 0; j < 4; ++j) {
        const int row = r0 + m * 16 + j;
        if (row >= M) continue;
        const float v = acc[m][n][j];
        if (EPI == EPI_BF16) {
          ((u16*)Cb)[(int64_t)row * ldc + col] = f2bf(v + b1v);
        } else if (EPI == EPI_BF16_RELU) {
          float t = v + b1v; t = t > 0.f ? t : 0.f;
          ((u16*)Cb)[(int64_t)row * ldc + col] = f2bf(t);
        } else if (EPI == EPI_F32) {
          ((float*)Cb)[(int64_t)row * ldc + col] = v;
        }
      }
    }
  }
}

// Merged QKV + rk projection.  896 blocks: [0,768) QKV (N=1536 over
// WqT|WkT|WvT, M=4096), [768,896) rk = pe@WrT (M=2048, N=512).  NW=2.
// V columns (which==2) are written DIRECTLY to vt (b,h,dh,l) as u16x4
// (j -> consecutive t), eliminating the separate transpose_v pass.
__global__ __launch_bounds__(256) void gemm_qkv_rk(
    const u16* __restrict__ xb, const u16* __restrict__ pe,
    const u16* __restrict__ WqkvT, const u16* __restrict__ WrT,
    char* __restrict__ qcBase, u16* __restrict__ vtOut,
    u16* __restrict__ rkOut, const float* __restrict__ biasAll)
{
  __shared__ __align__(16) u16 As[2][128 * BK];
  __shared__ __align__(16) u16 Bs[2][64 * BK];

  const bool isRk = blockIdx.x >= 768;
  const int bidl = isRk ? (blockIdx.x - 768) : blockIdx.x;
  const int m0 = isRk ? (bidl >> 3) * 128 : (bidl / 24) * 128;
  const int n0 = isRk ? (bidl & 7) * 64   : (bidl % 24) * 64;
  const u16* A  = isRk ? pe   : xb;
  const u16* Bt = isRk ? WrT  : WqkvT;

  const int tid  = threadIdx.x;
  const int lane = tid & 63;
  const int wid  = tid >> 6;
  const int wm = (wid >> 1) * 64;
  const int wn = (wid & 1) * 32;
  const int fr = lane & 15;
  const int fk = (lane >> 4) * 8;

  f32x4 acc[4][2];
#pragma unroll
  for (int m = 0; m < 4; ++m)
#pragma unroll
    for (int n = 0; n < 2; ++n) acc[m][n] = (f32x4){0.f, 0.f, 0.f, 0.f};

  auto STAGE = [&](int step, int buf) {
    const int kt = step * BK;
#pragma unroll
    for (int it = 0; it < 4; ++it) {
      const int off = (it * 256 + tid) * 8;
      const int r = off >> 6, c = off & (BK - 1);
      gld16(A + (int64_t)(m0 + r) * 512 + kt + c, &As[buf][off]);
    }
#pragma unroll
    for (int it = 0; it < 2; ++it) {
      const int off = (it * 256 + tid) * 8;
      const int r = off >> 6, c = off & (BK - 1);
      gld16(Bt + (int64_t)(n0 + r) * 512 + kt + c, &Bs[buf][off]);
    }
  };

  STAGE(0, 0);
  for (int s = 0; s < 8; ++s) {      // K = 512
    const int cur = s & 1;
    __syncthreads();
    if (s + 1 < 8) STAGE(s + 1, cur ^ 1);

#pragma unroll
    for (int kk = 0; kk < BK; kk += 32) {
      bf16x8 af[4], bfv[2];
#pragma unroll
      for (int m = 0; m < 4; ++m)
        af[m] = *(const bf16x8*)&As[cur][(wm + m * 16 + fr) * BK + kk + fk];
#pragma unroll
      for (int n = 0; n < 2; ++n)
        bfv[n] = *(const bf16x8*)&Bs[cur][(wn + n * 16 + fr) * BK + kk + fk];
#pragma unroll
      for (int m = 0; m < 4; ++m)
#pragma unroll
        for (int n = 0; n < 2; ++n)
          acc[m][n] = __builtin_amdgcn_mfma_f32_16x16x32_bf16(af[m], bfv[n], acc[m][n], 0, 0, 0);
    }
  }

  const int r0 = m0 + wm + (lane >> 4) * 4;
  const int c0 = n0 + wn + fr;
#pragma unroll
  for (int m = 0; m < 4; ++m) {
#pragma unroll
    for (int n = 0; n < 2; ++n) {
      const int col = c0 + n * 16;
      if (isRk) {
#pragma unroll
        for (int j = 0; j < 4; ++j)
          rkOut[(int64_t)(r0 + m * 16 + j) * 512 + col] = f2bf(acc[m][n][j]);
      } else {
        const int which = col >> 9, cc = col & 511;
        if (which == 2) {
          // v -> vt[b][h][c][t] directly; j gives consecutive t
          u16x4 pv;
          const float bv = biasAll[1536 + cc];
#pragma unroll
          for (int j = 0; j < 4; ++j) pv[j] = f2bf(acc[m][n][j] + bv);
          const int row0 = r0 + m * 16;
          const int bb = row0 >> 10, t = row0 & 1023;
          *(u16x4*)&vtOut[(int64_t)(bb * 8 + (cc >> 6)) * 65536
                          + (cc & 63) * 1024 + t] = pv;
        } else {
          const int slot = (which == 0) ? 0 : 2;   // 0:qc(+qr) 2:kb
#pragma unroll
          for (int j = 0; j < 4; ++j) {
            const int row = r0 + m * 16 + j;
            const float v = acc[m][n][j];
            u16* dst = (u16*)qcBase + (int64_t)slot * 2097152
                     + (int64_t)row * 512 + cc;
            *dst = f2bf(v + biasAll[slot * 512 + cc]);
            if (which == 0)                        // slot 1: qr
              dst[2097152] = f2bf(v + biasAll[512 + cc]);
          }
        }
      }
    }
  }
}

// ---------------------------------------------------------------------------
// ALL preprocessing in one dispatch (9474 blocks).
// ---------------------------------------------------------------------------
__global__ __launch_bounds__(256) void prep_all(
    const float* __restrict__ x,
    const float* __restrict__ Wq, const float* __restrict__ Wk,
    const float* __restrict__ Wv, const float* __restrict__ Wo,
    const float* __restrict__ Wr, const float* __restrict__ W1,
    const float* __restrict__ W2,
    const float* __restrict__ bq, const float* __restrict__ cb,
    const float* __restrict__ rb, const float* __restrict__ bk,
    const float* __restrict__ bv, char* __restrict__ wsb)
{
  __shared__ float t[32][33];
  const int bid = blockIdx.x;
  const int tid = threadIdx.x;
  if (bid < 4096) {                       // pe
    u16* pe = (u16*)(wsb + 20480);
    int idx = bid * 256 + tid;
    int i = idx >> 9, j = idx & 511, jf = j & 255;
    float inv = __expf(-(float)jf * (2.0f / 512.0f) * 9.210340371976184f);
    float arg = (float)(i - 1024) * inv;
    pe[idx] = f2bf((j < 256) ? __sinf(arg) : __cosf(arg));
  } else if (bid < 6144) {                // convert x
    u16* xb = (u16*)(wsb + 8933376);
    int idx = (bid - 4096) * 256 + tid;
    f32x4 v = ((const f32x4*)x)[idx];
    u16x4 o;
    o[0] = f2bf(v[0]); o[1] = f2bf(v[1]); o[2] = f2bf(v[2]); o[3] = f2bf(v[3]);
    ((u16x4*)xb)[idx] = o;
  } else if (bid < 6146) {                // biases (bqc|bqr|bkv contiguous)
    int i = (bid - 6144) * 256 + tid;
    float* bqc = (float*)wsb;
    if (i < 512) {
      bqc[i]        = bq[i] + cb[i];
      bqc[512 + i]  = bq[i] + rb[i];
      bqc[1024 + i] = bk[i];
      bqc[1536 + i] = bv[i];
    }
  } else {                                // transposes
    const int tl0 = bid - 6146;
    const float* src; u16* dst;
    int ldi, ldo, bx, by;
    if (tl0 < 1280) {
      const int wsel = tl0 >> 8, tl = tl0 & 255;
      bx = tl & 15; by = tl >> 4; ldi = 512; ldo = 512;
      src = (wsel == 0) ? Wq : (wsel == 1) ? Wk : (wsel == 2) ? Wv
          : (wsel == 3) ? Wo : Wr;
      dst = (u16*)(wsb + 2117632 + (int64_t)wsel * 524288);
    } else if (tl0 < 2304) {
      const int tl = tl0 - 1280;
      bx = tl & 63; by = tl >> 6; ldi = 2048; ldo = 512;
      src = W1; dst = (u16*)(wsb + 4739072);
    } else {
      const int tl = tl0 - 2304;
      bx = tl & 15; by = tl >> 4; ldi = 512; ldo = 2048;
      src = W2; dst = (u16*)(wsb + 6836224);
    }
    const int xx = tid & 31, yy = tid >> 5;   // 32 x 8
    const int r0 = by * 32, c0 = bx * 32;
#pragma unroll
    for (int i = 0; i < 32; i += 8)
      t[yy + i][xx] = src[(int64_t)(r0 + yy + i) * ldi + c0 + xx];
    __syncthreads();
#pragma unroll
    for (int i = 0; i < 32; i += 8)
      dst[(int64_t)(c0 + yy + i) * ldo + r0 + xx] = f2bf(t[xx][yy + i]);
  }
}

// LN over val = 2*(X1 + X2 + bias).  one wave/row, 4 rows/block, grid(1024).
template <int OUT_F32>
__global__ void layernorm_sum2_kernel(
    const float* __restrict__ X1, const float* __restrict__ X2,
    const float* __restrict__ bias,
    const float* __restrict__ sc, const float* __restrict__ bi,
    void* __restrict__ outv) {
  const int row = blockIdx.x * 4 + (threadIdx.x >> 6);
  const int lane = threadIdx.x & 63;
  const int64_t ro = (int64_t)row * 512;
  f32x4 a1 = ((const f32x4*)(X1 + ro))[lane];
  f32x4 a2 = ((const f32x4*)(X1 + ro))[lane + 64];
  f32x4 b1 = ((const f32x4*)(X2 + ro))[lane];
  f32x4 b2 = ((const f32x4*)(X2 + ro))[lane + 64];
  f32x4 c1 = ((const f32x4*)bias)[lane];
  f32x4 c2 = ((const f32x4*)bias)[lane + 64];
  f32x4 a, b;
#pragma unroll
  for (int e = 0; e < 4; ++e) {
    a[e] = 2.f * (a1[e] + b1[e] + c1[e]);
    b[e] = 2.f * (a2[e] + b2[e] + c2[e]);
  }
  float s = 0.f, q = 0.f;
#pragma unroll
  for (int e = 0; e < 4; ++e) { s += a[e] + b[e]; q += a[e]*a[e] + b[e]*b[e]; }
#pragma unroll
  for (int o = 32; o; o >>= 1) { s += __shfl_xor(s, o, 64); q += __shfl_xor(q, o, 64); }
  const float mu = s * (1.f / 512.f);
  const float var = q * (1.f / 512.f) - mu * mu;
  const float r = rsqrtf(var + 1e-6f);
  const int cc1 = lane * 4, cc2 = (lane + 64) * 4;
  f32x4 s1 = ((const f32x4*)sc)[lane], s2 = ((const f32x4*)sc)[lane + 64];
  f32x4 g1 = ((const f32x4*)bi)[lane], g2 = ((const f32x4*)bi)[lane + 64];
  if (OUT_F32) {
    float* out = (float*)outv;
    f32x4 o1, o2;
#pragma unroll
    for (int e = 0; e < 4; ++e) {
      o1[e] = (a[e] - mu) * r * s1[e] + g1[e];
      o2[e] = (b[e] - mu) * r * s2[e] + g2[e];
    }
    *(f32x4*)&out[ro + cc1] = o1;
    *(f32x4*)&out[ro + cc2] = o2;
  } else {
    u16* out = (u16*)outv;
    u16x4 o1, o2;
#pragma unroll
    for (int e = 0; e < 4; ++e) {
      o1[e] = f2bf((a[e] - mu) * r * s1[e] + g1[e]);
      o2[e] = f2bf((b[e] - mu) * r * s2[e] + g2[e]);
    }
    *(u16x4*)&out[ro + cc1] = o1;
    *(u16x4*)&out[ro + cc2] = o2;
  }
}

// ---------------------------------------------------------------------------
extern "C" void kernel_launch(void* const* d_in, const int* in_sizes, int n_in,
                              void* d_out, int out_size, void* d_ws, size_t ws_size,
                              hipStream_t stream) {
  const float* x    = (const float*)d_in[0];
  const float* Wq   = (const float*)d_in[1];
  const float* bq   = (const float*)d_in[2];
  const float* Wk   = (const float*)d_in[3];
  const float* bk   = (const float*)d_in[4];
  const float* Wv   = (const float*)d_in[5];
  const float* bv   = (const float*)d_in[6];
  const float* cb   = (const float*)d_in[7];
  const float* rb   = (const float*)d_in[8];
  const float* Wr   = (const float*)d_in[9];
  const float* Wo   = (const float*)d_in[10];
  const float* bo   = (const float*)d_in[11];
  const float* ln1s = (const float*)d_in[12];
  const float* ln1b = (const float*)d_in[13];
  const float* W1   = (const float*)d_in[14];
  const float* b1   = (const float*)d_in[15];
  const float* W2   = (const float*)d_in[16];
  const float* b2   = (const float*)d_in[17];
  const float* ln2s = (const float*)d_in[18];
  const float* ln2b = (const float*)d_in[19];
  (void)in_sizes; (void)n_in; (void)out_size; (void)ws_size;

  char* ws = (char*)d_ws;
  float* bqc = (float*)(ws + 0);          // bqc|bqr|bkv contiguous (2048 f32)
  u16* pe  = (u16*)(ws + 20480);          // 2048x512 bf16
  u16* WqT = (u16*)(ws + 2117632);        // Wq|Wk|Wv T contiguous (1536x512)
  u16* WoT = (u16*)(ws + 3690496);
  u16* WrT = (u16*)(ws + 4214784);
  u16* W1T = (u16*)(ws + 4739072);        // 2048x512
  u16* W2T = (u16*)(ws + 6836224);        // 512x2048
  u16* xb  = (u16*)(ws + 8933376);        // 4096x512 bf16
  u16* qc  = (u16*)(ws + 13127680);       // qc|qr|kb slots (+2097152 u16 each)
  u16* kb  = (u16*)(ws + 21516288);
  u16* vt  = (u16*)(ws + 29904896);       // (b,h,dh,l) written by QKV epilogue
  u16* rk  = (u16*)(ws + 34099200);       // 2048x512
  u16* ob  = (u16*)(ws + 36196352);       // 4096x512 (attn out)
  char* scratch = ws + 40390656;
  float* pA  = (float*)scratch;                   // 4096x512 fp32
  float* pB  = (float*)(ws + 13127680);           // qc region (dead post-attn)
  u16*   ln1 = (u16*)(scratch + 8388608);         // 4096x512 bf16
  u16*   ffn1= (u16*)(scratch + 12582912);        // 4096x2048 bf16
  const int64_t zPart = (int64_t)((char*)pB - (char*)pA);

  const dim3 blk(256);

  prep_all<<<dim3(9474), blk, 0, stream>>>(x, Wq, Wk, Wv, Wo, Wr, W1, W2,
                                           bq, cb, rb, bk, bv, ws);

  // fused q/qr/k/v projection (v -> vt directly) + rk projection
  gemm_qkv_rk<<<dim3(896), blk, 0, stream>>>(xb, pe, WqT, WrT,
                                             (char*)qc, vt, rk, bqc);

  // fused attention (256 blocks x 512 threads; XCD = bid&7)
  fused_attn_kernel<<<dim3(256), dim3(512), 0, stream>>>(
      qc, qc + 2097152, kb, vt, rk, ob);

  // o@Wo, K-split z=2 -> partials; LN1 folds +bo, x2, sum
  gemm_bt<EPI_F32, 2><<<dim3(8, 32, 2), blk, 0, stream>>>(
      ob, 256, 512, WoT, 256, 512, (char*)pA, zPart, 512, nullptr, 0,
      4096, 512, 256);
  layernorm_sum2_kernel<0><<<dim3(1024), blk, 0, stream>>>(
      pA, pB, bo, ln1s, ln1b, ln1);
  // FFN
  gemm_bt<EPI_BF16_RELU, 4><<<dim3(16, 32, 1), blk, 0, stream>>>(
      ln1, 0, 512, W1T, 0, 512, (char*)ffn1, 0, 2048, b1, 0, 4096, 2048, 512);
  gemm_bt<EPI_F32, 2><<<dim3(8, 32, 2), blk, 0, stream>>>(
      ffn1, 1024, 2048, W2T, 1024, 2048, (char*)pA, zPart, 512, nullptr, 0,
      4096, 512, 1024);
  layernorm_sum2_kernel<1><<<dim3(1024), blk, 0, stream>>>(
      pA, pB, b2, ln2s, ln2b, d_out);
}

// Round 16
// 135.969 us; speedup vs baseline: 1.0475x; 1.0132x over previous
//
#include <hip/hip_runtime.h>
#include <stdint.h>

// ---------------------------------------------------------------------------
// TransformerXL encoder layer.  Inputs fp32, OUTPUT fp32.  b=4 l=1024 d=512
// h=8 dh=64.
// Round 16: pure revert to round 13 (best known, 136.0us).  T5 setprio was
// null->negative (waves lockstep, m190-style); removed.  Attn at structural
// floor (~42us): KV-split x2, dbuf/one-barrier, 32-row intensity, DPP, T5
// all bracketed it at 42+-1us.  GEMM tail at 2-phase ceiling (8-phase is
// regime-gated to shapes this problem doesn't have).
// rel shift closed form: shifted[t,j] = R[t, 1024 + j - t],  R = (q+rb)@rk^T.
// ---------------------------------------------------------------------------

typedef unsigned short u16;
typedef __attribute__((ext_vector_type(8))) __bf16 bf16x8;
typedef __attribute__((ext_vector_type(8))) unsigned short u16x8;
typedef __attribute__((ext_vector_type(4))) float f32x4;
typedef __attribute__((ext_vector_type(4))) unsigned short u16x4;

#define BK 64

static __device__ __forceinline__ u16 f2bf(float f) {
  union { float f; unsigned int i; } v; v.f = f;
  unsigned int r = v.i + 0x7FFFu + ((v.i >> 16) & 1u);
  return (u16)(r >> 16);
}

// global->LDS direct copy, 16B per lane (lds dest must be linear in lane id).
static __device__ __forceinline__ void gld16(const void* g, void* l) {
  __builtin_amdgcn_global_load_lds(
      (__attribute__((address_space(1))) void*)(uintptr_t)g,
      (__attribute__((address_space(3))) void*)(uintptr_t)l,
      16, 0, 0);
}

// swizzled u16 index into a [rows][64]-u16 LDS tile (16B chunk ^= row&7).
static __device__ __forceinline__ int swzIdx(int r, int ch) {
  return (r << 6) + (((ch ^ (r & 7)) & 7) << 3);
}

// DPP-based max step over the 16-lane DPP row (VALU pipe, not LDS pipe).
template <int CTRL>
static __device__ __forceinline__ float fmax_dpp(float t) {
  int m = __builtin_amdgcn_mov_dpp(__builtin_bit_cast(int, t), CTRL, 0xF, 0xF, true);
  return fmaxf(t, __builtin_bit_cast(float, m));
}

// ---------------------------------------------------------------------------
// Fused attention.  256 blocks x 512 threads.  bid: h = bid&7 (XCD), s=bid>>3:
// qt = s&7, b = s>>3.  Waves 0-3 own q-rows [qt*128, +64), waves 4-7 the next
// 64.  Both halves consume the SAME kv tile -> kb/vt LDS shared.
// Double-buffered kb/vt/rk: one barrier per tile; WRITE(t+1) overlaps
// COMPUTE(t); ISSUE(t+2) gives loads a full iteration to land.
// ---------------------------------------------------------------------------
__global__ __launch_bounds__(512) void fused_attn_kernel(
    const u16* __restrict__ qc, const u16* __restrict__ qr,
    const u16* __restrict__ kb, const u16* __restrict__ vt,
    const u16* __restrict__ rk, u16* __restrict__ ob)
{
  __shared__ __align__(16) u16 kbLds[2][64 * 64];      // k tile  [j][d]
  __shared__ __align__(16) u16 vtLds[2][64 * 64];      // vt tile [c][j]
  __shared__ __align__(16) u16 rkLds[2][2][128 * 64];  // [buf][half] rk band
  __shared__ __align__(16) u16 pLds[8][16 * 64];       // per-wave P

  const int tid  = threadIdx.x;
  const int lane = tid & 63;
  const int w    = tid >> 6;          // 0..7
  const int th   = w >> 2;            // q-tile half
  const int wl   = w & 3;             // wave within half
  const int g    = lane >> 4;
  const int li   = lane & 15;

  const int bid = blockIdx.x;         // XCD = bid&7 = h
  const int h   = bid & 7;
  const int s   = bid >> 3;
  const int qt  = s & 7;
  const int b   = s >> 3;
  const int t0  = qt * 128 + th * 64; // this half's q-tile base

  const int64_t qoff = (int64_t)b * 524288 + (int64_t)(t0 + wl * 16 + li) * 512
                     + h * 64 + g * 8;
  bf16x8 qcf[2], qrf[2];
  qcf[0] = *(const bf16x8*)(qc + qoff);
  qcf[1] = *(const bf16x8*)(qc + qoff + 32);
  qrf[0] = *(const bf16x8*)(qr + qoff);
  qrf[1] = *(const bf16x8*)(qr + qoff + 32);

  const u16* kbB = kb + (int64_t)b * 524288 + h * 64;
  const u16* vtB = vt + (int64_t)(b * 8 + h) * 65536;
  const u16* rkB = rk + h * 64;

  bf16x8 ones;
#pragma unroll
  for (int e = 0; e < 8; ++e) ((u16*)&ones)[e] = 0x3F80;

  float m_[4] = {-1e30f, -1e30f, -1e30f, -1e30f};
  f32x4 o_[4];
  f32x4 o4 = (f32x4){0.f, 0.f, 0.f, 0.f};        // row-sum accumulator (= l)
#pragma unroll
  for (int n = 0; n < 4; ++n) o_[n] = (f32x4){0.f, 0.f, 0.f, 0.f};

  const int base = li - 4 * g + 15;            // in [3,30]
  int  srcj[4];
  bool cndj[4];
#pragma unroll
  for (int j = 0; j < 4; ++j) {
    srcj[j] = ((base - j) & 15) | (lane & 48);
    cndj[j] = (base - j) < 16;
  }

  const int bhalf = tid >> 8;
  const int tid2  = tid & 255;

  // two static staging reg sets (rule #20: no runtime indexing)
  u16x8 skA, svA, srA[4], skB, svB, srB[4];

  auto ISSUE = [&](int itx, u16x8& skR, u16x8& svR, u16x8* srR) {
    const int j0 = itx * 64;
    const int r = tid >> 3, ch = tid & 7;
    skR = *(const u16x8*)(kbB + (int64_t)(j0 + r) * 512 + ch * 8);
    svR = *(const u16x8*)(vtB + (int64_t)r * 1024 + j0 + ch * 8);
    const int ub = 1024 + j0 - (qt * 128 + bhalf * 64) - 63;   // >= 1
#pragma unroll
    for (int p = 0; p < 4; ++p) {
      const int flat = p * 256 + tid2, r2 = flat >> 3, ch2 = flat & 7;
      int u = ub + r2; u = u < 2047 ? u : 2047;
      srR[p] = *(const u16x8*)(rkB + (int64_t)u * 512 + ch2 * 8);
    }
  };

  auto WRITE = [&](u16* kbL, u16* vtL, u16* rkL,
                   const u16x8& skR, const u16x8& svR, const u16x8* srR) {
    const int r = tid >> 3, ch = tid & 7;
    *(u16x8*)&kbL[swzIdx(r, ch)] = skR;
    *(u16x8*)&vtL[swzIdx(r, ch)] = svR;
#pragma unroll
    for (int p = 0; p < 4; ++p) {
      const int flat = p * 256 + tid2, r2 = flat >> 3, ch2 = flat & 7;
      *(u16x8*)&rkL[bhalf * (128 * 64) + swzIdx(r2, ch2)] = srR[p];
    }
  };

  auto COMPUTE = [&](const u16* kbL, const u16* vtL, const u16* rkL) {
    // ---- content logits ----
    f32x4 c_[4];
#pragma unroll
    for (int n = 0; n < 4; ++n) c_[n] = (f32x4){0.f, 0.f, 0.f, 0.f};
#pragma unroll
    for (int kc = 0; kc < 2; ++kc) {
      const int chn = kc * 4 + g;
#pragma unroll
      for (int n = 0; n < 4; ++n) {
        bf16x8 bb = *(const bf16x8*)&kbL[swzIdx(n * 16 + li, chn)];
        c_[n] = __builtin_amdgcn_mfma_f32_16x16x32_bf16(qcf[kc], bb, c_[n], 0, 0, 0);
      }
    }
    // ---- rel band (this half's band) ----
    f32x4 r_[5];
#pragma unroll
    for (int f = 0; f < 5; ++f) r_[f] = (f32x4){0.f, 0.f, 0.f, 0.f};
#pragma unroll
    for (int kc = 0; kc < 2; ++kc) {
      const int chn = kc * 4 + g;
#pragma unroll
      for (int f = 0; f < 5; ++f) {
        const int lr = f * 16 + li + 48 - 16 * wl;
        bf16x8 bb = *(const bf16x8*)&rkL[th * (128 * 64) + swzIdx(lr, chn)];
        r_[f] = __builtin_amdgcn_mfma_f32_16x16x32_bf16(qrf[kc], bb, r_[f], 0, 0, 0);
      }
    }
    // ---- band merge: 20 bpermutes + local select ----
    float vsh[5][4];
#pragma unroll
    for (int f = 0; f < 5; ++f)
#pragma unroll
      for (int j = 0; j < 4; ++j)
        vsh[f][j] = __shfl(r_[f][j], srcj[j], 64);
    float sv2[4][4];
#pragma unroll
    for (int n = 0; n < 4; ++n)
#pragma unroll
      for (int j = 0; j < 4; ++j)
        sv2[n][j] = c_[n][j] + (cndj[j] ? vsh[n][j] : vsh[n + 1][j]);

    // ---- online softmax: DPP max-reduce + exact defer-rescale ----
    float tmax[4];
    bool grow = false;
#pragma unroll
    for (int j = 0; j < 4; ++j) {
      float t = fmaxf(fmaxf(sv2[0][j], sv2[1][j]), fmaxf(sv2[2][j], sv2[3][j]));
      t = fmax_dpp<0xB1>(t);    // quad_perm [1,0,3,2]
      t = fmax_dpp<0x4E>(t);    // quad_perm [2,3,0,1]
      t = fmax_dpp<0x124>(t);   // row_ror:4
      t = fmax_dpp<0x128>(t);   // row_ror:8
      tmax[j] = t;
      grow = grow || (t > m_[j]);
    }
    if (__any(grow)) {
      float al[4];
#pragma unroll
      for (int j = 0; j < 4; ++j) {
        const float nm = fmaxf(m_[j], tmax[j]);
        al[j] = __expf(m_[j] - nm);
        m_[j] = nm;
      }
#pragma unroll
      for (int n = 0; n < 4; ++n)
#pragma unroll
        for (int j = 0; j < 4; ++j) o_[n][j] *= al[j];
#pragma unroll
      for (int j = 0; j < 4; ++j) o4[j] *= al[j];
    }
    u16* pw = pLds[w];
#pragma unroll
    for (int n = 0; n < 4; ++n)
#pragma unroll
      for (int j = 0; j < 4; ++j) {
        const float p = __expf(sv2[n][j] - m_[j]);
        const int rw = g * 4 + j, col = n * 16 + li;
        pw[(rw << 6) + ((((col >> 3) ^ (rw & 7)) & 7) << 3) + (col & 7)] = f2bf(p);
      }

    // ---- PV (+ ones column accumulates l) ----
#pragma unroll
    for (int kc = 0; kc < 2; ++kc) {
      const int chn = kc * 4 + g;
      bf16x8 pa = *(const bf16x8*)&pw[swzIdx(li, chn)];
#pragma unroll
      for (int n = 0; n < 4; ++n) {
        bf16x8 vb = *(const bf16x8*)&vtL[swzIdx(n * 16 + li, chn)];
        o_[n] = __builtin_amdgcn_mfma_f32_16x16x32_bf16(pa, vb, o_[n], 0, 0, 0);
      }
      o4 = __builtin_amdgcn_mfma_f32_16x16x32_bf16(pa, ones, o4, 0, 0, 0);
    }
  };

  // prologue: tile 0 -> buf0, issue tile 1 into set B
  ISSUE(0, skA, svA, srA);
  WRITE(kbLds[0], vtLds[0], &rkLds[0][0][0], skA, svA, srA);
  ISSUE(1, skB, svB, srB);
  __syncthreads();

  for (int ii = 0; ii < 8; ++ii) {
    const int it = ii * 2;
    // even tile: compute buf0; write tile it+1 (set B) -> buf1; issue it+2 -> A
    COMPUTE(kbLds[0], vtLds[0], &rkLds[0][0][0]);
    WRITE(kbLds[1], vtLds[1], &rkLds[1][0][0], skB, svB, srB);
    if (it + 2 < 16) ISSUE(it + 2, skA, svA, srA);
    __syncthreads();
    // odd tile: compute buf1; write tile it+2 (set A) -> buf0; issue it+3 -> B
    COMPUTE(kbLds[1], vtLds[1], &rkLds[1][0][0]);
    if (it + 2 < 16) WRITE(kbLds[0], vtLds[0], &rkLds[0][0][0], skA, svA, srA);
    if (it + 3 < 16) ISSUE(it + 3, skB, svB, srB);
    __syncthreads();
  }

  float inv[4];
#pragma unroll
  for (int j = 0; j < 4; ++j) inv[j] = 1.f / o4[j];
  u16* obB = ob + (int64_t)b * 524288 + (int64_t)(t0 + wl * 16) * 512 + h * 64;
#pragma unroll
  for (int n = 0; n < 4; ++n)
#pragma unroll
    for (int j = 0; j < 4; ++j)
      obB[(int64_t)(g * 4 + j) * 512 + n * 16 + li] = f2bf(o_[n][j] * inv[j]);
}

enum { EPI_BF16 = 0, EPI_BF16_RELU = 1, EPI_F32 = 2 };

// C[m,n] = sum_k A[m,k] * Bt[n,k].  Tile 128 x (NW*32).  gld_lds staging,
// double-buffered 2-phase.
template <int EPI, int NW>
__global__ __launch_bounds__(256) void gemm_bt(
    const u16* __restrict__ A, int64_t zA, int lda,
    const u16* __restrict__ Bt, int64_t zB, int ldb,
    char* __restrict__ Cb, int64_t zCbytes, int ldc,
    const float* __restrict__ bias1, int zbias,
    int M, int N, int K)
{
  __shared__ __align__(16) u16 As[2][128 * BK];
  __shared__ __align__(16) u16 Bs[2][NW * 32 * BK];

  const int z = blockIdx.z;
  A  += (int64_t)z * zA;
  Bt += (int64_t)z * zB;
  Cb += (int64_t)z * zCbytes;

  const int m0 = blockIdx.y * 128;
  const int n0 = blockIdx.x * (NW * 32);

  const int tid  = threadIdx.x;
  const int lane = tid & 63;
  const int wid  = tid >> 6;
  const int wm = (wid >> 1) * 64;
  const int wn = (wid & 1) * (NW * 16);
  const int fr = lane & 15;
  const int fk = (lane >> 4) * 8;

  f32x4 acc[4][NW];
#pragma unroll
  for (int m = 0; m < 4; ++m)
#pragma unroll
    for (int n = 0; n < NW; ++n) acc[m][n] = (f32x4){0.f, 0.f, 0.f, 0.f};

  const int nsteps = K >> 6;
  auto STAGE = [&](int step, int buf) {
    const int kt = step * BK;
#pragma unroll
    for (int it = 0; it < 4; ++it) {
      const int off = (it * 256 + tid) * 8;
      const int r = off >> 6, c = off & (BK - 1);
      int gr = m0 + r; if (gr > M - 1) gr = M - 1;
      gld16(A + (int64_t)gr * lda + kt + c, &As[buf][off]);
    }
#pragma unroll
    for (int it = 0; it < NW; ++it) {
      const int off = (it * 256 + tid) * 8;
      const int r = off >> 6, c = off & (BK - 1);
      int gr = n0 + r; if (gr > N - 1) gr = N - 1;
      gld16(Bt + (int64_t)gr * ldb + kt + c, &Bs[buf][off]);
    }
  };

  STAGE(0, 0);
  for (int s = 0; s < nsteps; ++s) {
    const int cur = s & 1;
    __syncthreads();
    if (s + 1 < nsteps) STAGE(s + 1, cur ^ 1);

#pragma unroll
    for (int kk = 0; kk < BK; kk += 32) {
      bf16x8 af[4], bfv[NW];
#pragma unroll
      for (int m = 0; m < 4; ++m)
        af[m] = *(const bf16x8*)&As[cur][(wm + m * 16 + fr) * BK + kk + fk];
#pragma unroll
      for (int n = 0; n < NW; ++n)
        bfv[n] = *(const bf16x8*)&Bs[cur][(wn + n * 16 + fr) * BK + kk + fk];
#pragma unroll
      for (int m = 0; m < 4; ++m)
#pragma unroll
        for (int n = 0; n < NW; ++n)
          acc[m][n] = __builtin_amdgcn_mfma_f32_16x16x32_bf16(af[m], bfv[n], acc[m][n], 0, 0, 0);
    }
  }

  const int r0 = m0 + wm + (lane >> 4) * 4;
  const int c0 = n0 + wn + fr;
#pragma unroll
  for (int m = 0; m < 4; ++m) {
#pragma unroll
    for (int n = 0; n < NW; ++n) {
      const int col = c0 + n * 16;
      if (col >= N) continue;
      float b1v = 0.f;
      if (EPI == EPI_BF16 || EPI == EPI_BF16_RELU) {
        if (bias1) b1v = bias1[z * zbias + col];
      }
#pragma unroll
      for (int j = 0; j < 4; ++j) {
        const int row = r0 + m * 16 + j;
        if (row >= M) continue;
        const float v = acc[m][n][j];
        if (EPI == EPI_BF16) {
          ((u16*)Cb)[(int64_t)row * ldc + col] = f2bf(v + b1v);
        } else if (EPI == EPI_BF16_RELU) {
          float t = v + b1v; t = t > 0.f ? t : 0.f;
          ((u16*)Cb)[(int64_t)row * ldc + col] = f2bf(t);
        } else if (EPI == EPI_F32) {
          ((float*)Cb)[(int64_t)row * ldc + col] = v;
        }
      }
    }
  }
}

// Merged QKV + rk projection.  896 blocks: [0,768) QKV (N=1536 over
// WqT|WkT|WvT, M=4096), [768,896) rk = pe@WrT (M=2048, N=512).  NW=2.
// V columns (which==2) are written DIRECTLY to vt (b,h,dh,l) as u16x4
// (j -> consecutive t), eliminating the separate transpose_v pass.
__global__ __launch_bounds__(256) void gemm_qkv_rk(
    const u16* __restrict__ xb, const u16* __restrict__ pe,
    const u16* __restrict__ WqkvT, const u16* __restrict__ WrT,
    char* __restrict__ qcBase, u16* __restrict__ vtOut,
    u16* __restrict__ rkOut, const float* __restrict__ biasAll)
{
  __shared__ __align__(16) u16 As[2][128 * BK];
  __shared__ __align__(16) u16 Bs[2][64 * BK];

  const bool isRk = blockIdx.x >= 768;
  const int bidl = isRk ? (blockIdx.x - 768) : blockIdx.x;
  const int m0 = isRk ? (bidl >> 3) * 128 : (bidl / 24) * 128;
  const int n0 = isRk ? (bidl & 7) * 64   : (bidl % 24) * 64;
  const u16* A  = isRk ? pe   : xb;
  const u16* Bt = isRk ? WrT  : WqkvT;

  const int tid  = threadIdx.x;
  const int lane = tid & 63;
  const int wid  = tid >> 6;
  const int wm = (wid >> 1) * 64;
  const int wn = (wid & 1) * 32;
  const int fr = lane & 15;
  const int fk = (lane >> 4) * 8;

  f32x4 acc[4][2];
#pragma unroll
  for (int m = 0; m < 4; ++m)
#pragma unroll
    for (int n = 0; n < 2; ++n) acc[m][n] = (f32x4){0.f, 0.f, 0.f, 0.f};

  auto STAGE = [&](int step, int buf) {
    const int kt = step * BK;
#pragma unroll
    for (int it = 0; it < 4; ++it) {
      const int off = (it * 256 + tid) * 8;
      const int r = off >> 6, c = off & (BK - 1);
      gld16(A + (int64_t)(m0 + r) * 512 + kt + c, &As[buf][off]);
    }
#pragma unroll
    for (int it = 0; it < 2; ++it) {
      const int off = (it * 256 + tid) * 8;
      const int r = off >> 6, c = off & (BK - 1);
      gld16(Bt + (int64_t)(n0 + r) * 512 + kt + c, &Bs[buf][off]);
    }
  };

  STAGE(0, 0);
  for (int s = 0; s < 8; ++s) {      // K = 512
    const int cur = s & 1;
    __syncthreads();
    if (s + 1 < 8) STAGE(s + 1, cur ^ 1);

#pragma unroll
    for (int kk = 0; kk < BK; kk += 32) {
      bf16x8 af[4], bfv[2];
#pragma unroll
      for (int m = 0; m < 4; ++m)
        af[m] = *(const bf16x8*)&As[cur][(wm + m * 16 + fr) * BK + kk + fk];
#pragma unroll
      for (int n = 0; n < 2; ++n)
        bfv[n] = *(const bf16x8*)&Bs[cur][(wn + n * 16 + fr) * BK + kk + fk];
#pragma unroll
      for (int m = 0; m < 4; ++m)
#pragma unroll
        for (int n = 0; n < 2; ++n)
          acc[m][n] = __builtin_amdgcn_mfma_f32_16x16x32_bf16(af[m], bfv[n], acc[m][n], 0, 0, 0);
    }
  }

  const int r0 = m0 + wm + (lane >> 4) * 4;
  const int c0 = n0 + wn + fr;
#pragma unroll
  for (int m = 0; m < 4; ++m) {
#pragma unroll
    for (int n = 0; n < 2; ++n) {
      const int col = c0 + n * 16;
      if (isRk) {
#pragma unroll
        for (int j = 0; j < 4; ++j)
          rkOut[(int64_t)(r0 + m * 16 + j) * 512 + col] = f2bf(acc[m][n][j]);
      } else {
        const int which = col >> 9, cc = col & 511;
        if (which == 2) {
          // v -> vt[b][h][c][t] directly; j gives consecutive t
          u16x4 pv;
          const float bv = biasAll[1536 + cc];
#pragma unroll
          for (int j = 0; j < 4; ++j) pv[j] = f2bf(acc[m][n][j] + bv);
          const int row0 = r0 + m * 16;
          const int bb = row0 >> 10, t = row0 & 1023;
          *(u16x4*)&vtOut[(int64_t)(bb * 8 + (cc >> 6)) * 65536
                          + (cc & 63) * 1024 + t] = pv;
        } else {
          const int slot = (which == 0) ? 0 : 2;   // 0:qc(+qr) 2:kb
#pragma unroll
          for (int j = 0; j < 4; ++j) {
            const int row = r0 + m * 16 + j;
            const float v = acc[m][n][j];
            u16* dst = (u16*)qcBase + (int64_t)slot * 2097152
                     + (int64_t)row * 512 + cc;
            *dst = f2bf(v + biasAll[slot * 512 + cc]);
            if (which == 0)                        // slot 1: qr
              dst[2097152] = f2bf(v + biasAll[512 + cc]);
          }
        }
      }
    }
  }
}

// ---------------------------------------------------------------------------
// ALL preprocessing in one dispatch (9474 blocks).
// ---------------------------------------------------------------------------
__global__ __launch_bounds__(256) void prep_all(
    const float* __restrict__ x,
    const float* __restrict__ Wq, const float* __restrict__ Wk,
    const float* __restrict__ Wv, const float* __restrict__ Wo,
    const float* __restrict__ Wr, const float* __restrict__ W1,
    const float* __restrict__ W2,
    const float* __restrict__ bq, const float* __restrict__ cb,
    const float* __restrict__ rb, const float* __restrict__ bk,
    const float* __restrict__ bv, char* __restrict__ wsb)
{
  __shared__ float t[32][33];
  const int bid = blockIdx.x;
  const int tid = threadIdx.x;
  if (bid < 4096) {                       // pe
    u16* pe = (u16*)(wsb + 20480);
    int idx = bid * 256 + tid;
    int i = idx >> 9, j = idx & 511, jf = j & 255;
    float inv = __expf(-(float)jf * (2.0f / 512.0f) * 9.210340371976184f);
    float arg = (float)(i - 1024) * inv;
    pe[idx] = f2bf((j < 256) ? __sinf(arg) : __cosf(arg));
  } else if (bid < 6144) {                // convert x
    u16* xb = (u16*)(wsb + 8933376);
    int idx = (bid - 4096) * 256 + tid;
    f32x4 v = ((const f32x4*)x)[idx];
    u16x4 o;
    o[0] = f2bf(v[0]); o[1] = f2bf(v[1]); o[2] = f2bf(v[2]); o[3] = f2bf(v[3]);
    ((u16x4*)xb)[idx] = o;
  } else if (bid < 6146) {                // biases (bqc|bqr|bkv contiguous)
    int i = (bid - 6144) * 256 + tid;
    float* bqc = (float*)wsb;
    if (i < 512) {
      bqc[i]        = bq[i] + cb[i];
      bqc[512 + i]  = bq[i] + rb[i];
      bqc[1024 + i] = bk[i];
      bqc[1536 + i] = bv[i];
    }
  } else {                                // transposes
    const int tl0 = bid - 6146;
    const float* src; u16* dst;
    int ldi, ldo, bx, by;
    if (tl0 < 1280) {
      const int wsel = tl0 >> 8, tl = tl0 & 255;
      bx = tl & 15; by = tl >> 4; ldi = 512; ldo = 512;
      src = (wsel == 0) ? Wq : (wsel == 1) ? Wk : (wsel == 2) ? Wv
          : (wsel == 3) ? Wo : Wr;
      dst = (u16*)(wsb + 2117632 + (int64_t)wsel * 524288);
    } else if (tl0 < 2304) {
      const int tl = tl0 - 1280;
      bx = tl & 63; by = tl >> 6; ldi = 2048; ldo = 512;
      src = W1; dst = (u16*)(wsb + 4739072);
    } else {
      const int tl = tl0 - 2304;
      bx = tl & 15; by = tl >> 4; ldi = 512; ldo = 2048;
      src = W2; dst = (u16*)(wsb + 6836224);
    }
    const int xx = tid & 31, yy = tid >> 5;   // 32 x 8
    const int r0 = by * 32, c0 = bx * 32;
#pragma unroll
    for (int i = 0; i < 32; i += 8)
      t[yy + i][xx] = src[(int64_t)(r0 + yy + i) * ldi + c0 + xx];
    __syncthreads();
#pragma unroll
    for (int i = 0; i < 32; i += 8)
      dst[(int64_t)(c0 + yy + i) * ldo + r0 + xx] = f2bf(t[xx][yy + i]);
  }
}

// LN over val = 2*(X1 + X2 + bias).  one wave/row, 4 rows/block, grid(1024).
template <int OUT_F32>
__global__ void layernorm_sum2_kernel(
    const float* __restrict__ X1, const float* __restrict__ X2,
    const float* __restrict__ bias,
    const float* __restrict__ sc, const float* __restrict__ bi,
    void* __restrict__ outv) {
  const int row = blockIdx.x * 4 + (threadIdx.x >> 6);
  const int lane = threadIdx.x & 63;
  const int64_t ro = (int64_t)row * 512;
  f32x4 a1 = ((const f32x4*)(X1 + ro))[lane];
  f32x4 a2 = ((const f32x4*)(X1 + ro))[lane + 64];
  f32x4 b1 = ((const f32x4*)(X2 + ro))[lane];
  f32x4 b2 = ((const f32x4*)(X2 + ro))[lane + 64];
  f32x4 c1 = ((const f32x4*)bias)[lane];
  f32x4 c2 = ((const f32x4*)bias)[lane + 64];
  f32x4 a, b;
#pragma unroll
  for (int e = 0; e < 4; ++e) {
    a[e] = 2.f * (a1[e] + b1[e] + c1[e]);
    b[e] = 2.f * (a2[e] + b2[e] + c2[e]);
  }
  float s = 0.f, q = 0.f;
#pragma unroll
  for (int e = 0; e < 4; ++e) { s += a[e] + b[e]; q += a[e]*a[e] + b[e]*b[e]; }
#pragma unroll
  for (int o = 32; o; o >>= 1) { s += __shfl_xor(s, o, 64); q += __shfl_xor(q, o, 64); }
  const float mu = s * (1.f / 512.f);
  const float var = q * (1.f / 512.f) - mu * mu;
  const float r = rsqrtf(var + 1e-6f);
  const int cc1 = lane * 4, cc2 = (lane + 64) * 4;
  f32x4 s1 = ((const f32x4*)sc)[lane], s2 = ((const f32x4*)sc)[lane + 64];
  f32x4 g1 = ((const f32x4*)bi)[lane], g2 = ((const f32x4*)bi)[lane + 64];
  if (OUT_F32) {
    float* out = (float*)outv;
    f32x4 o1, o2;
#pragma unroll
    for (int e = 0; e < 4; ++e) {
      o1[e] = (a[e] - mu) * r * s1[e] + g1[e];
      o2[e] = (b[e] - mu) * r * s2[e] + g2[e];
    }
    *(f32x4*)&out[ro + cc1] = o1;
    *(f32x4*)&out[ro + cc2] = o2;
  } else {
    u16* out = (u16*)outv;
    u16x4 o1, o2;
#pragma unroll
    for (int e = 0; e < 4; ++e) {
      o1[e] = f2bf((a[e] - mu) * r * s1[e] + g1[e]);
      o2[e] = f2bf((b[e] - mu) * r * s2[e] + g2[e]);
    }
    *(u16x4*)&out[ro + cc1] = o1;
    *(u16x4*)&out[ro + cc2] = o2;
  }
}

// ---------------------------------------------------------------------------
extern "C" void kernel_launch(void* const* d_in, const int* in_sizes, int n_in,
                              void* d_out, int out_size, void* d_ws, size_t ws_size,
                              hipStream_t stream) {
  const float* x    = (const float*)d_in[0];
  const float* Wq   = (const float*)d_in[1];
  const float* bq   = (const float*)d_in[2];
  const float* Wk   = (const float*)d_in[3];
  const float* bk   = (const float*)d_in[4];
  const float* Wv   = (const float*)d_in[5];
  const float* bv   = (const float*)d_in[6];
  const float* cb   = (const float*)d_in[7];
  const float* rb   = (const float*)d_in[8];
  const float* Wr   = (const float*)d_in[9];
  const float* Wo   = (const float*)d_in[10];
  const float* bo   = (const float*)d_in[11];
  const float* ln1s = (const float*)d_in[12];
  const float* ln1b = (const float*)d_in[13];
  const float* W1   = (const float*)d_in[14];
  const float* b1   = (const float*)d_in[15];
  const float* W2   = (const float*)d_in[16];
  const float* b2   = (const float*)d_in[17];
  const float* ln2s = (const float*)d_in[18];
  const float* ln2b = (const float*)d_in[19];
  (void)in_sizes; (void)n_in; (void)out_size; (void)ws_size;

  char* ws = (char*)d_ws;
  float* bqc = (float*)(ws + 0);          // bqc|bqr|bkv contiguous (2048 f32)
  u16* pe  = (u16*)(ws + 20480);          // 2048x512 bf16
  u16* WqT = (u16*)(ws + 2117632);        // Wq|Wk|Wv T contiguous (1536x512)
  u16* WoT = (u16*)(ws + 3690496);
  u16* WrT = (u16*)(ws + 4214784);
  u16* W1T = (u16*)(ws + 4739072);        // 2048x512
  u16* W2T = (u16*)(ws + 6836224);        // 512x2048
  u16* xb  = (u16*)(ws + 8933376);        // 4096x512 bf16
  u16* qc  = (u16*)(ws + 13127680);       // qc|qr|kb slots (+2097152 u16 each)
  u16* kb  = (u16*)(ws + 21516288);
  u16* vt  = (u16*)(ws + 29904896);       // (b,h,dh,l) written by QKV epilogue
  u16* rk  = (u16*)(ws + 34099200);       // 2048x512
  u16* ob  = (u16*)(ws + 36196352);       // 4096x512 (attn out)
  char* scratch = ws + 40390656;
  float* pA  = (float*)scratch;                   // 4096x512 fp32
  float* pB  = (float*)(ws + 13127680);           // qc region (dead post-attn)
  u16*   ln1 = (u16*)(scratch + 8388608);         // 4096x512 bf16
  u16*   ffn1= (u16*)(scratch + 12582912);        // 4096x2048 bf16
  const int64_t zPart = (int64_t)((char*)pB - (char*)pA);

  const dim3 blk(256);

  prep_all<<<dim3(9474), blk, 0, stream>>>(x, Wq, Wk, Wv, Wo, Wr, W1, W2,
                                           bq, cb, rb, bk, bv, ws);

  // fused q/qr/k/v projection (v -> vt directly) + rk projection
  gemm_qkv_rk<<<dim3(896), blk, 0, stream>>>(xb, pe, WqT, WrT,
                                             (char*)qc, vt, rk, bqc);

  // fused attention (256 blocks x 512 threads; XCD = bid&7)
  fused_attn_kernel<<<dim3(256), dim3(512), 0, stream>>>(
      qc, qc + 2097152, kb, vt, rk, ob);

  // o@Wo, K-split z=2 -> partials; LN1 folds +bo, x2, sum
  gemm_bt<EPI_F32, 2><<<dim3(8, 32, 2), blk, 0, stream>>>(
      ob, 256, 512, WoT, 256, 512, (char*)pA, zPart, 512, nullptr, 0,
      4096, 512, 256);
  layernorm_sum2_kernel<0><<<dim3(1024), blk, 0, stream>>>(
      pA, pB, bo, ln1s, ln1b, ln1);
  // FFN
  gemm_bt<EPI_BF16_RELU, 4><<<dim3(16, 32, 1), blk, 0, stream>>>(
      ln1, 0, 512, W1T, 0, 512, (char*)ffn1, 0, 2048, b1, 0, 4096, 2048, 512);
  gemm_bt<EPI_F32, 2><<<dim3(8, 32, 2), blk, 0, stream>>>(
      ffn1, 1024, 2048, W2T, 1024, 2048, (char*)pA, zPart, 512, nullptr, 0,
      4096, 512, 1024);
  layernorm_sum2_kernel<1><<<dim3(1024), blk, 0, stream>>>(
      pA, pB, b2, ln2s, ln2b, d_out);
}